// Round 5
// baseline (277.853 us; speedup 1.0000x reference)
//
#include <hip/hip_runtime.h>
#include <math.h>

#define LRELU(m) ((m) > 0.0f ? (m) : 0.2f * (m))

// ---------------- CSR build ----------------

__global__ void k_hist(const int* __restrict__ dst, const float* __restrict__ ea,
                       int* __restrict__ degi, float* __restrict__ easum, int E) {
    int e = blockIdx.x * blockDim.x + threadIdx.x;
    if (e >= E) return;
    int d = dst[e];
    atomicAdd(&degi[d], 1);
    atomicAdd(&easum[d], ea[e]);
}

__global__ void k_scan1(const int* __restrict__ degi, int* __restrict__ row_ptr,
                        int* __restrict__ blocksum, int N) {
    __shared__ int sm[256];
    int t = threadIdx.x;
    int i = blockIdx.x * 256 + t;
    int v = (i < N) ? degi[i] : 0;
    sm[t] = v;
    __syncthreads();
    #pragma unroll
    for (int off = 1; off < 256; off <<= 1) {
        int add = (t >= off) ? sm[t - off] : 0;
        __syncthreads();
        sm[t] += add;
        __syncthreads();
    }
    if (i < N) row_ptr[i] = sm[t] - v;   // exclusive
    if (t == 255) blocksum[blockIdx.x] = sm[255];
}

__global__ void k_scan2(int* __restrict__ blocksum, int nb) {
    __shared__ int sm[256];
    int t = threadIdx.x;
    int v = (t < nb) ? blocksum[t] : 0;
    sm[t] = v;
    __syncthreads();
    #pragma unroll
    for (int off = 1; off < 256; off <<= 1) {
        int add = (t >= off) ? sm[t - off] : 0;
        __syncthreads();
        sm[t] += add;
        __syncthreads();
    }
    if (t < nb) blocksum[t] = sm[t] - v;
}

__global__ void k_scan3(int* __restrict__ row_ptr, const int* __restrict__ blocksum,
                        int* __restrict__ cursor, int N) {
    int i = blockIdx.x * 256 + threadIdx.x;
    if (i >= N) return;
    int r = row_ptr[i] + blocksum[blockIdx.x];
    row_ptr[i] = r;
    cursor[i] = r;
}

__global__ void k_scatter(const int* __restrict__ src, const int* __restrict__ dst,
                          const float* __restrict__ ea, int* __restrict__ cursor,
                          int* __restrict__ csr_src, float* __restrict__ csr_ea, int E) {
    int e = blockIdx.x * blockDim.x + threadIdx.x;
    if (e >= E) return;
    int d = dst[e];
    int pos = atomicAdd(&cursor[d], 1);
    csr_src[pos] = src[e];
    csr_ea[pos] = ea[e];
}

// loop_ea = easum/max(deg,1)
__global__ void k_loopea(const int* __restrict__ degi, const float* __restrict__ easum,
                         float* __restrict__ loop_ea, int N) {
    int i = blockIdx.x * blockDim.x + threadIdx.x;
    if (i >= N) return;
    loop_ea[i] = easum[i] / fmaxf((float)degi[i], 1.0f);
}

// ---------------- layer 1 ----------------

// One wave per dst node, lane = 2 channels. Gathers only x[s] (16 B broadcast);
// vl = Wl1^T x[s] + bl1 recomputed in-register (Wl1 columns hoisted per lane).
// No max-subtraction (logits are O(0.3)); x4 unroll -> no loop-carried chain.
__global__ void k_l1_node(const int* __restrict__ csr_src, const float* __restrict__ csr_ea,
                          const int* __restrict__ row_ptr, const int* __restrict__ degi,
                          const float* __restrict__ x, const float* __restrict__ loop_ea,
                          const float* __restrict__ Wl1, const float* __restrict__ bl1,
                          const float* __restrict__ Wr1, const float* __restrict__ br1,
                          const float* __restrict__ We1, const float* __restrict__ att1,
                          const float* __restrict__ bias1, float* __restrict__ h1, int N) {
    int node = blockIdx.x * (blockDim.x >> 6) + (threadIdx.x >> 6);
    int lane = threadIdx.x & 63;
    if (node >= N) return;
    int c = lane * 2;
    // hoisted Wl1 columns c, c+1 and biases
    float wl00 = Wl1[c],       wl01 = Wl1[c + 1];
    float wl10 = Wl1[128 + c], wl11 = Wl1[128 + c + 1];
    float wl20 = Wl1[256 + c], wl21 = Wl1[256 + c + 1];
    float wl30 = Wl1[384 + c], wl31 = Wl1[384 + c + 1];
    float b0 = bl1[c], b1 = bl1[c + 1];
    // xr1[node] inline
    float4 xv = *(const float4*)(x + (size_t)node * 4);
    float r0 = br1[c], r1 = br1[c + 1];
    r0 = fmaf(xv.x, Wr1[c],       r0); r1 = fmaf(xv.x, Wr1[c + 1],       r1);
    r0 = fmaf(xv.y, Wr1[128 + c], r0); r1 = fmaf(xv.y, Wr1[128 + c + 1], r1);
    r0 = fmaf(xv.z, Wr1[256 + c], r0); r1 = fmaf(xv.z, Wr1[256 + c + 1], r1);
    r0 = fmaf(xv.w, Wr1[384 + c], r0); r1 = fmaf(xv.w, Wr1[384 + c + 1], r1);
    float2 we = *(const float2*)(We1 + c);
    float2 at = *(const float2*)(att1 + c);

    #define VL0(xs) fmaf((xs).w, wl30, fmaf((xs).z, wl20, fmaf((xs).y, wl10, fmaf((xs).x, wl00, b0))))
    #define VL1(xs) fmaf((xs).w, wl31, fmaf((xs).z, wl21, fmaf((xs).y, wl11, fmaf((xs).x, wl01, b1))))

    // self-loop
    float vx = VL0(xv), vy = VL1(xv);
    float eav = loop_ea[node];
    float p = LRELU(vx + r0 + eav * we.x) * at.x + LRELU(vy + r1 + eav * we.y) * at.y;
    p += __shfl_xor(p, 1); p += __shfl_xor(p, 2); p += __shfl_xor(p, 4);
    float a = __expf(p);
    float den = a, accx = a * vx, accy = a * vy;
    int start = row_ptr[node], deg = degi[node];
    int k = 0;
    for (; k + 4 <= deg; k += 4) {
        int s0 = csr_src[start + k],     s1 = csr_src[start + k + 1];
        int s2 = csr_src[start + k + 2], s3 = csr_src[start + k + 3];
        float e0 = csr_ea[start + k],     e1 = csr_ea[start + k + 1];
        float e2 = csr_ea[start + k + 2], e3 = csr_ea[start + k + 3];
        float4 x0 = *(const float4*)(x + (size_t)s0 * 4);
        float4 x1 = *(const float4*)(x + (size_t)s1 * 4);
        float4 x2 = *(const float4*)(x + (size_t)s2 * 4);
        float4 x3 = *(const float4*)(x + (size_t)s3 * 4);
        float v0x = VL0(x0), v0y = VL1(x0);
        float v1x = VL0(x1), v1y = VL1(x1);
        float v2x = VL0(x2), v2y = VL1(x2);
        float v3x = VL0(x3), v3y = VL1(x3);
        float p0 = LRELU(v0x + r0 + e0 * we.x) * at.x + LRELU(v0y + r1 + e0 * we.y) * at.y;
        float p1 = LRELU(v1x + r0 + e1 * we.x) * at.x + LRELU(v1y + r1 + e1 * we.y) * at.y;
        float p2 = LRELU(v2x + r0 + e2 * we.x) * at.x + LRELU(v2y + r1 + e2 * we.y) * at.y;
        float p3 = LRELU(v3x + r0 + e3 * we.x) * at.x + LRELU(v3y + r1 + e3 * we.y) * at.y;
        p0 += __shfl_xor(p0, 1); p1 += __shfl_xor(p1, 1); p2 += __shfl_xor(p2, 1); p3 += __shfl_xor(p3, 1);
        p0 += __shfl_xor(p0, 2); p1 += __shfl_xor(p1, 2); p2 += __shfl_xor(p2, 2); p3 += __shfl_xor(p3, 2);
        p0 += __shfl_xor(p0, 4); p1 += __shfl_xor(p1, 4); p2 += __shfl_xor(p2, 4); p3 += __shfl_xor(p3, 4);
        float a0 = __expf(p0), a1 = __expf(p1), a2 = __expf(p2), a3 = __expf(p3);
        den += (a0 + a1) + (a2 + a3);
        accx = fmaf(a0, v0x, accx); accy = fmaf(a0, v0y, accy);
        accx = fmaf(a1, v1x, accx); accy = fmaf(a1, v1y, accy);
        accx = fmaf(a2, v2x, accx); accy = fmaf(a2, v2y, accy);
        accx = fmaf(a3, v3x, accx); accy = fmaf(a3, v3y, accy);
    }
    for (; k < deg; ++k) {
        int s = csr_src[start + k];
        float ee = csr_ea[start + k];
        float4 xs = *(const float4*)(x + (size_t)s * 4);
        float vsx = VL0(xs), vsy = VL1(xs);
        float pp = LRELU(vsx + r0 + ee * we.x) * at.x + LRELU(vsy + r1 + ee * we.y) * at.y;
        pp += __shfl_xor(pp, 1); pp += __shfl_xor(pp, 2); pp += __shfl_xor(pp, 4);
        float aa = __expf(pp);
        den += aa;
        accx = fmaf(aa, vsx, accx);
        accy = fmaf(aa, vsy, accy);
    }
    #undef VL0
    #undef VL1
    float inv = 1.0f / den;
    float o0 = fmaf(accx, inv, bias1[c]);
    float o1 = fmaf(accy, inv, bias1[c + 1]);
    o0 = o0 > 0.0f ? o0 : expm1f(o0);
    o1 = o1 > 0.0f ? o1 : expm1f(o1);
    *(float2*)(h1 + (size_t)node * 128 + c) = make_float2(o0, o1);
}

// ---------------- layer 2 ----------------

// thread = (node, j): computes xl2 and xr2 together with float4 row loads
__global__ void k_l2_lin(const float* __restrict__ h1, const float* __restrict__ Wl2,
                         const float* __restrict__ bl2, const float* __restrict__ Wr2,
                         const float* __restrict__ br2, float* __restrict__ xl2,
                         float* __restrict__ xr2, int N) {
    int t = blockIdx.x * blockDim.x + threadIdx.x;
    if (t >= N * 8) return;
    int i = t >> 3, j = t & 7;
    float accl = bl2[j], accr = br2[j];
    const float* row = h1 + (size_t)i * 128;
    #pragma unroll 4
    for (int k = 0; k < 128; k += 4) {
        float4 hv = *(const float4*)(row + k);
        accl = fmaf(hv.x, Wl2[k * 8 + j], accl);       accr = fmaf(hv.x, Wr2[k * 8 + j], accr);
        accl = fmaf(hv.y, Wl2[(k + 1) * 8 + j], accl); accr = fmaf(hv.y, Wr2[(k + 1) * 8 + j], accr);
        accl = fmaf(hv.z, Wl2[(k + 2) * 8 + j], accl); accr = fmaf(hv.z, Wr2[(k + 2) * 8 + j], accr);
        accl = fmaf(hv.w, Wl2[(k + 3) * 8 + j], accl); accr = fmaf(hv.w, Wr2[(k + 3) * 8 + j], accr);
    }
    xl2[t] = accl;
    xr2[t] = accr;
}

// One wave per dst node, lane = edge. No atomics: writes h2 coalesced.
__global__ void k_l2_node(const int* __restrict__ csr_src, const float* __restrict__ csr_ea,
                          const int* __restrict__ row_ptr, const int* __restrict__ degi,
                          const float* __restrict__ xl2, const float* __restrict__ xr2,
                          const float* __restrict__ loop_ea,
                          const float* __restrict__ We2, const float* __restrict__ att2,
                          const float* __restrict__ bias2, float* __restrict__ h2, int N) {
    int node = blockIdx.x * (blockDim.x >> 6) + (threadIdx.x >> 6);
    int lane = threadIdx.x & 63;
    if (node >= N) return;
    float4 ra = *(const float4*)(xr2 + (size_t)node * 8);
    float4 rb = *(const float4*)(xr2 + (size_t)node * 8 + 4);
    float r[8] = {ra.x, ra.y, ra.z, ra.w, rb.x, rb.y, rb.z, rb.w};
    float we[8], at[8];
    #pragma unroll
    for (int cc = 0; cc < 8; ++cc) { we[cc] = We2[cc]; at[cc] = att2[cc]; }
    int start = row_ptr[node], deg = degi[node];
    int total = deg + 1;          // + self loop
    float den = 0.0f;
    float acc[8];
    #pragma unroll
    for (int cc = 0; cc < 8; ++cc) acc[cc] = 0.0f;
    for (int base = 0; base < total; base += 64) {
        int e = base + lane;
        float a = 0.0f;
        float l[8];
        #pragma unroll
        for (int cc = 0; cc < 8; ++cc) l[cc] = 0.0f;
        if (e < total) {
            int s; float eav;
            if (e < deg) { s = csr_src[start + e]; eav = csr_ea[start + e]; }
            else         { s = node;               eav = loop_ea[node]; }
            float4 la = *(const float4*)(xl2 + (size_t)s * 8);
            float4 lb = *(const float4*)(xl2 + (size_t)s * 8 + 4);
            l[0] = la.x; l[1] = la.y; l[2] = la.z; l[3] = la.w;
            l[4] = lb.x; l[5] = lb.y; l[6] = lb.z; l[7] = lb.w;
            float p = 0.0f;
            #pragma unroll
            for (int cc = 0; cc < 8; ++cc) {
                float m = l[cc] + r[cc] + eav * we[cc];
                p = fmaf(LRELU(m), at[cc], p);
            }
            a = __expf(p);
        }
        float w0 = a;
        float w1 = a * l[0], w2 = a * l[1], w3 = a * l[2], w4 = a * l[3];
        float w5 = a * l[4], w6 = a * l[5], w7 = a * l[6], w8 = a * l[7];
        #pragma unroll
        for (int off = 1; off < 64; off <<= 1) {
            w0 += __shfl_xor(w0, off);
            w1 += __shfl_xor(w1, off); w2 += __shfl_xor(w2, off);
            w3 += __shfl_xor(w3, off); w4 += __shfl_xor(w4, off);
            w5 += __shfl_xor(w5, off); w6 += __shfl_xor(w6, off);
            w7 += __shfl_xor(w7, off); w8 += __shfl_xor(w8, off);
        }
        den += w0;
        acc[0] += w1; acc[1] += w2; acc[2] += w3; acc[3] += w4;
        acc[4] += w5; acc[5] += w6; acc[6] += w7; acc[7] += w8;
    }
    if (lane == 0) {
        float inv = 1.0f / den;
        float o[8];
        #pragma unroll
        for (int cc = 0; cc < 8; ++cc) {
            float v = fmaf(acc[cc], inv, bias2[cc]);
            o[cc] = v > 0.0f ? v : expm1f(v);
        }
        *(float4*)(h2 + (size_t)node * 8)     = make_float4(o[0], o[1], o[2], o[3]);
        *(float4*)(h2 + (size_t)node * 8 + 4) = make_float4(o[4], o[5], o[6], o[7]);
    }
}

// One block per graph; batch is sorted -> binary-search the segment. No atomics.
// Fused mean + @W3 + b3.
__global__ void k_pool(const float* __restrict__ h2, const int* __restrict__ batch,
                       const float* __restrict__ W3, const float* __restrict__ b3,
                       float* __restrict__ out, int N) {
    int g = blockIdx.x;
    int lo = 0, hi = N;
    while (lo < hi) { int mid = (lo + hi) >> 1; if (batch[mid] < g) lo = mid + 1; else hi = mid; }
    int start = lo;
    int lo2 = start, hi2 = N;
    while (lo2 < hi2) { int mid = (lo2 + hi2) >> 1; if (batch[mid] < g + 1) lo2 = mid + 1; else hi2 = mid; }
    int end = lo2;
    int cnt = end - start;
    int t = threadIdx.x;
    int c = t & 7, rg = t >> 3;   // 32 row groups x 8 channels
    float s = 0.0f;
    for (int i = start + rg; i < end; i += 32) s += h2[(size_t)i * 8 + c];
    __shared__ float sm[256];
    sm[t] = s;
    __syncthreads();
    #pragma unroll
    for (int off = 16; off >= 1; off >>= 1) {
        if (rg < off) sm[t] += sm[t + off * 8];
        __syncthreads();
    }
    if (t == 0) {
        float inv = 1.0f / fmaxf((float)cnt, 1.0f);
        float acc = b3[0];
        #pragma unroll
        for (int cc = 0; cc < 8; ++cc) acc = fmaf(sm[cc] * inv, W3[cc], acc);
        out[g] = acc;
    }
}

extern "C" void kernel_launch(void* const* d_in, const int* in_sizes, int n_in,
                              void* d_out, int out_size, void* d_ws, size_t ws_size,
                              hipStream_t stream) {
    const float* x     = (const float*)d_in[0];
    const int*   ei    = (const int*)d_in[1];
    const float* ea    = (const float*)d_in[2];
    const int*   batch = (const int*)d_in[3];
    const float* Wl1 = (const float*)d_in[4];
    const float* bl1 = (const float*)d_in[5];
    const float* Wr1 = (const float*)d_in[6];
    const float* br1 = (const float*)d_in[7];
    const float* We1 = (const float*)d_in[8];
    const float* att1 = (const float*)d_in[9];
    const float* bias1 = (const float*)d_in[10];
    const float* Wl2 = (const float*)d_in[11];
    const float* bl2 = (const float*)d_in[12];
    const float* Wr2 = (const float*)d_in[13];
    const float* br2 = (const float*)d_in[14];
    const float* We2 = (const float*)d_in[15];
    const float* att2 = (const float*)d_in[16];
    const float* bias2 = (const float*)d_in[17];
    const float* W3 = (const float*)d_in[18];
    const float* b3 = (const float*)d_in[19];

    const int N  = in_sizes[0] / 4;
    const int E  = in_sizes[1] / 2;
    const int G  = out_size;
    const int* src = ei;
    const int* dst = ei + E;
    const int nb = (N + 255) / 256;   // <= 256 for N <= 65536

    float* w = (float*)d_ws;
    // Zone A: accumulators (memset to 0 every call)
    int*   degi   = (int*)w;  w += N;
    float* easum  = w;        w += N;
    size_t zoneA_bytes = (size_t)((char*)w - (char*)d_ws);
    // Zone B: fully overwritten each call
    int*   row_ptr  = (int*)w; w += N;
    int*   cursor   = (int*)w; w += N;
    int*   blocksum = (int*)w; w += 256;
    float* loop_ea  = w;       w += N;
    float* h1  = w;            w += (size_t)N * 128;
    float* xl2 = w;            w += (size_t)N * 8;
    float* xr2 = w;            w += (size_t)N * 8;
    int*   csr_src = (int*)w;  w += E;
    float* csr_ea  = w;        w += E;
    float* h2 = h1;            // h1 dead after k_l2_lin

    hipMemsetAsync(d_ws, 0, zoneA_bytes, stream);

    // CSR build
    k_hist<<<(E + 255) / 256, 256, 0, stream>>>(dst, ea, degi, easum, E);
    k_scan1<<<nb, 256, 0, stream>>>(degi, row_ptr, blocksum, N);
    k_scan2<<<1, 256, 0, stream>>>(blocksum, nb);
    k_scan3<<<nb, 256, 0, stream>>>(row_ptr, blocksum, cursor, N);
    k_scatter<<<(E + 255) / 256, 256, 0, stream>>>(src, dst, ea, cursor, csr_src, csr_ea, E);
    k_loopea<<<nb, 256, 0, stream>>>(degi, easum, loop_ea, N);

    // layer 1
    k_l1_node<<<(N + 3) / 4, 256, 0, stream>>>(csr_src, csr_ea, row_ptr, degi, x, loop_ea,
                                               Wl1, bl1, Wr1, br1, We1, att1, bias1, h1, N);
    // layer 2
    k_l2_lin<<<((size_t)N * 8 + 255) / 256, 256, 0, stream>>>(h1, Wl2, bl2, Wr2, br2,
                                                              xl2, xr2, N);
    k_l2_node<<<(N + 3) / 4, 256, 0, stream>>>(csr_src, csr_ea, row_ptr, degi, xl2, xr2,
                                               loop_ea, We2, att2, bias2, h2, N);
    // pool + final linear
    k_pool<<<G, 256, 0, stream>>>(h2, batch, W3, b3, (float*)d_out, N);
}

// Round 6
// 237.960 us; speedup vs baseline: 1.1676x; 1.1676x over previous
//
#include <hip/hip_runtime.h>
#include <math.h>

#define LRELU(m) ((m) > 0.0f ? (m) : 0.2f * (m))

// ---------------- CSR build ----------------

// in-degree histogram only (1 atomic per edge), x4 coarsened
__global__ void k_hist(const int* __restrict__ dst, int* __restrict__ degi, int E) {
    int e = (blockIdx.x * blockDim.x + threadIdx.x) * 4;
    if (e + 4 <= E) {
        int4 d4 = *(const int4*)(dst + e);
        atomicAdd(&degi[d4.x], 1);
        atomicAdd(&degi[d4.y], 1);
        atomicAdd(&degi[d4.z], 1);
        atomicAdd(&degi[d4.w], 1);
    } else {
        for (; e < E; ++e) atomicAdd(&degi[dst[e]], 1);
    }
}

__global__ void k_scan1(const int* __restrict__ degi, int* __restrict__ row_ptr,
                        int* __restrict__ blocksum, int N) {
    __shared__ int sm[256];
    int t = threadIdx.x;
    int i = blockIdx.x * 256 + t;
    int v = (i < N) ? degi[i] : 0;
    sm[t] = v;
    __syncthreads();
    #pragma unroll
    for (int off = 1; off < 256; off <<= 1) {
        int add = (t >= off) ? sm[t - off] : 0;
        __syncthreads();
        sm[t] += add;
        __syncthreads();
    }
    if (i < N) row_ptr[i] = sm[t] - v;   // exclusive
    if (t == 255) blocksum[blockIdx.x] = sm[255];
}

__global__ void k_scan2(int* __restrict__ blocksum, int nb) {
    __shared__ int sm[256];
    int t = threadIdx.x;
    int v = (t < nb) ? blocksum[t] : 0;
    sm[t] = v;
    __syncthreads();
    #pragma unroll
    for (int off = 1; off < 256; off <<= 1) {
        int add = (t >= off) ? sm[t - off] : 0;
        __syncthreads();
        sm[t] += add;
        __syncthreads();
    }
    if (t < nb) blocksum[t] = sm[t] - v;
}

__global__ void k_scan3(int* __restrict__ row_ptr, const int* __restrict__ blocksum,
                        int* __restrict__ cursor, int N, int E) {
    int i = blockIdx.x * 256 + threadIdx.x;
    if (i == 0) row_ptr[N] = E;
    if (i >= N) return;
    int r = row_ptr[i] + blocksum[blockIdx.x];
    row_ptr[i] = r;
    cursor[i] = r;
}

// scatter (src, ea) as one packed 8B store per edge
__global__ void k_scatter(const int* __restrict__ src, const int* __restrict__ dst,
                          const float* __restrict__ ea, int* __restrict__ cursor,
                          int2* __restrict__ csr, int E) {
    int e = blockIdx.x * blockDim.x + threadIdx.x;
    if (e >= E) return;
    int d = dst[e];
    int pos = atomicAdd(&cursor[d], 1);
    csr[pos] = make_int2(src[e], __float_as_int(ea[e]));
}

// loop_ea[i] = (sum of incoming ea) / max(deg,1)  — contiguous segment read, no atomics
__global__ void k_loopea(const int* __restrict__ row_ptr, const int2* __restrict__ csr,
                         float* __restrict__ loop_ea, int N) {
    int i = blockIdx.x * blockDim.x + threadIdx.x;
    if (i >= N) return;
    int start = row_ptr[i], end = row_ptr[i + 1];
    float s = 0.0f;
    for (int k = start; k < end; ++k) s += __int_as_float(csr[k].y);
    loop_ea[i] = s / fmaxf((float)(end - start), 1.0f);
}

// ---------------- layer 1 ----------------

// One wave per dst node, lane = 2 channels. Gathers only x[s] (16 B broadcast);
// vl = Wl1^T x[s] + bl1 recomputed in-register (Wl1 columns hoisted per lane).
// No max-subtraction (logits are O(0.3)); x4 unroll -> no loop-carried chain.
__global__ void k_l1_node(const int2* __restrict__ csr, const int* __restrict__ row_ptr,
                          const float* __restrict__ x, const float* __restrict__ loop_ea,
                          const float* __restrict__ Wl1, const float* __restrict__ bl1,
                          const float* __restrict__ Wr1, const float* __restrict__ br1,
                          const float* __restrict__ We1, const float* __restrict__ att1,
                          const float* __restrict__ bias1, float* __restrict__ h1, int N) {
    int node = blockIdx.x * (blockDim.x >> 6) + (threadIdx.x >> 6);
    int lane = threadIdx.x & 63;
    if (node >= N) return;
    int c = lane * 2;
    float wl00 = Wl1[c],       wl01 = Wl1[c + 1];
    float wl10 = Wl1[128 + c], wl11 = Wl1[128 + c + 1];
    float wl20 = Wl1[256 + c], wl21 = Wl1[256 + c + 1];
    float wl30 = Wl1[384 + c], wl31 = Wl1[384 + c + 1];
    float b0 = bl1[c], b1 = bl1[c + 1];
    float4 xv = *(const float4*)(x + (size_t)node * 4);
    float r0 = br1[c], r1 = br1[c + 1];
    r0 = fmaf(xv.x, Wr1[c],       r0); r1 = fmaf(xv.x, Wr1[c + 1],       r1);
    r0 = fmaf(xv.y, Wr1[128 + c], r0); r1 = fmaf(xv.y, Wr1[128 + c + 1], r1);
    r0 = fmaf(xv.z, Wr1[256 + c], r0); r1 = fmaf(xv.z, Wr1[256 + c + 1], r1);
    r0 = fmaf(xv.w, Wr1[384 + c], r0); r1 = fmaf(xv.w, Wr1[384 + c + 1], r1);
    float2 we = *(const float2*)(We1 + c);
    float2 at = *(const float2*)(att1 + c);

    #define VL0(xs) fmaf((xs).w, wl30, fmaf((xs).z, wl20, fmaf((xs).y, wl10, fmaf((xs).x, wl00, b0))))
    #define VL1(xs) fmaf((xs).w, wl31, fmaf((xs).z, wl21, fmaf((xs).y, wl11, fmaf((xs).x, wl01, b1))))

    // self-loop
    float vx = VL0(xv), vy = VL1(xv);
    float eav = loop_ea[node];
    float p = LRELU(vx + r0 + eav * we.x) * at.x + LRELU(vy + r1 + eav * we.y) * at.y;
    p += __shfl_xor(p, 1); p += __shfl_xor(p, 2); p += __shfl_xor(p, 4);
    float a = __expf(p);
    float den = a, accx = a * vx, accy = a * vy;
    int start = row_ptr[node], deg = row_ptr[node + 1] - start;
    int k = 0;
    for (; k + 4 <= deg; k += 4) {
        int2 pr0 = csr[start + k],     pr1 = csr[start + k + 1];
        int2 pr2 = csr[start + k + 2], pr3 = csr[start + k + 3];
        float e0 = __int_as_float(pr0.y), e1 = __int_as_float(pr1.y);
        float e2 = __int_as_float(pr2.y), e3 = __int_as_float(pr3.y);
        float4 x0 = *(const float4*)(x + (size_t)pr0.x * 4);
        float4 x1 = *(const float4*)(x + (size_t)pr1.x * 4);
        float4 x2 = *(const float4*)(x + (size_t)pr2.x * 4);
        float4 x3 = *(const float4*)(x + (size_t)pr3.x * 4);
        float v0x = VL0(x0), v0y = VL1(x0);
        float v1x = VL0(x1), v1y = VL1(x1);
        float v2x = VL0(x2), v2y = VL1(x2);
        float v3x = VL0(x3), v3y = VL1(x3);
        float p0 = LRELU(v0x + r0 + e0 * we.x) * at.x + LRELU(v0y + r1 + e0 * we.y) * at.y;
        float p1 = LRELU(v1x + r0 + e1 * we.x) * at.x + LRELU(v1y + r1 + e1 * we.y) * at.y;
        float p2 = LRELU(v2x + r0 + e2 * we.x) * at.x + LRELU(v2y + r1 + e2 * we.y) * at.y;
        float p3 = LRELU(v3x + r0 + e3 * we.x) * at.x + LRELU(v3y + r1 + e3 * we.y) * at.y;
        p0 += __shfl_xor(p0, 1); p1 += __shfl_xor(p1, 1); p2 += __shfl_xor(p2, 1); p3 += __shfl_xor(p3, 1);
        p0 += __shfl_xor(p0, 2); p1 += __shfl_xor(p1, 2); p2 += __shfl_xor(p2, 2); p3 += __shfl_xor(p3, 2);
        p0 += __shfl_xor(p0, 4); p1 += __shfl_xor(p1, 4); p2 += __shfl_xor(p2, 4); p3 += __shfl_xor(p3, 4);
        float a0 = __expf(p0), a1 = __expf(p1), a2 = __expf(p2), a3 = __expf(p3);
        den += (a0 + a1) + (a2 + a3);
        accx = fmaf(a0, v0x, accx); accy = fmaf(a0, v0y, accy);
        accx = fmaf(a1, v1x, accx); accy = fmaf(a1, v1y, accy);
        accx = fmaf(a2, v2x, accx); accy = fmaf(a2, v2y, accy);
        accx = fmaf(a3, v3x, accx); accy = fmaf(a3, v3y, accy);
    }
    for (; k < deg; ++k) {
        int2 pr = csr[start + k];
        float ee = __int_as_float(pr.y);
        float4 xs = *(const float4*)(x + (size_t)pr.x * 4);
        float vsx = VL0(xs), vsy = VL1(xs);
        float pp = LRELU(vsx + r0 + ee * we.x) * at.x + LRELU(vsy + r1 + ee * we.y) * at.y;
        pp += __shfl_xor(pp, 1); pp += __shfl_xor(pp, 2); pp += __shfl_xor(pp, 4);
        float aa = __expf(pp);
        den += aa;
        accx = fmaf(aa, vsx, accx);
        accy = fmaf(aa, vsy, accy);
    }
    #undef VL0
    #undef VL1
    float inv = 1.0f / den;
    float o0 = fmaf(accx, inv, bias1[c]);
    float o1 = fmaf(accy, inv, bias1[c + 1]);
    o0 = o0 > 0.0f ? o0 : expm1f(o0);
    o1 = o1 > 0.0f ? o1 : expm1f(o1);
    *(float2*)(h1 + (size_t)node * 128 + c) = make_float2(o0, o1);
}

// ---------------- layer 2 ----------------

// thread = (node, j): computes xl2 and xr2 together with float4 row loads
__global__ void k_l2_lin(const float* __restrict__ h1, const float* __restrict__ Wl2,
                         const float* __restrict__ bl2, const float* __restrict__ Wr2,
                         const float* __restrict__ br2, float* __restrict__ xl2,
                         float* __restrict__ xr2, int N) {
    int t = blockIdx.x * blockDim.x + threadIdx.x;
    if (t >= N * 8) return;
    int i = t >> 3, j = t & 7;
    float accl = bl2[j], accr = br2[j];
    const float* row = h1 + (size_t)i * 128;
    #pragma unroll 4
    for (int k = 0; k < 128; k += 4) {
        float4 hv = *(const float4*)(row + k);
        accl = fmaf(hv.x, Wl2[k * 8 + j], accl);       accr = fmaf(hv.x, Wr2[k * 8 + j], accr);
        accl = fmaf(hv.y, Wl2[(k + 1) * 8 + j], accl); accr = fmaf(hv.y, Wr2[(k + 1) * 8 + j], accr);
        accl = fmaf(hv.z, Wl2[(k + 2) * 8 + j], accl); accr = fmaf(hv.z, Wr2[(k + 2) * 8 + j], accr);
        accl = fmaf(hv.w, Wl2[(k + 3) * 8 + j], accl); accr = fmaf(hv.w, Wr2[(k + 3) * 8 + j], accr);
    }
    xl2[t] = accl;
    xr2[t] = accr;
}

// One wave per dst node, lane = edge. No atomics: writes h2 coalesced.
__global__ void k_l2_node(const int2* __restrict__ csr, const int* __restrict__ row_ptr,
                          const float* __restrict__ xl2, const float* __restrict__ xr2,
                          const float* __restrict__ loop_ea,
                          const float* __restrict__ We2, const float* __restrict__ att2,
                          const float* __restrict__ bias2, float* __restrict__ h2, int N) {
    int node = blockIdx.x * (blockDim.x >> 6) + (threadIdx.x >> 6);
    int lane = threadIdx.x & 63;
    if (node >= N) return;
    float4 ra = *(const float4*)(xr2 + (size_t)node * 8);
    float4 rb = *(const float4*)(xr2 + (size_t)node * 8 + 4);
    float r[8] = {ra.x, ra.y, ra.z, ra.w, rb.x, rb.y, rb.z, rb.w};
    float we[8], at[8];
    #pragma unroll
    for (int cc = 0; cc < 8; ++cc) { we[cc] = We2[cc]; at[cc] = att2[cc]; }
    int start = row_ptr[node], deg = row_ptr[node + 1] - start;
    int total = deg + 1;          // + self loop
    float den = 0.0f;
    float acc[8];
    #pragma unroll
    for (int cc = 0; cc < 8; ++cc) acc[cc] = 0.0f;
    for (int base = 0; base < total; base += 64) {
        int e = base + lane;
        float a = 0.0f;
        float l[8];
        #pragma unroll
        for (int cc = 0; cc < 8; ++cc) l[cc] = 0.0f;
        if (e < total) {
            int s; float eav;
            if (e < deg) { int2 pr = csr[start + e]; s = pr.x; eav = __int_as_float(pr.y); }
            else         { s = node;                 eav = loop_ea[node]; }
            float4 la = *(const float4*)(xl2 + (size_t)s * 8);
            float4 lb = *(const float4*)(xl2 + (size_t)s * 8 + 4);
            l[0] = la.x; l[1] = la.y; l[2] = la.z; l[3] = la.w;
            l[4] = lb.x; l[5] = lb.y; l[6] = lb.z; l[7] = lb.w;
            float p = 0.0f;
            #pragma unroll
            for (int cc = 0; cc < 8; ++cc) {
                float m = l[cc] + r[cc] + eav * we[cc];
                p = fmaf(LRELU(m), at[cc], p);
            }
            a = __expf(p);
        }
        float w0 = a;
        float w1 = a * l[0], w2 = a * l[1], w3 = a * l[2], w4 = a * l[3];
        float w5 = a * l[4], w6 = a * l[5], w7 = a * l[6], w8 = a * l[7];
        #pragma unroll
        for (int off = 1; off < 64; off <<= 1) {
            w0 += __shfl_xor(w0, off);
            w1 += __shfl_xor(w1, off); w2 += __shfl_xor(w2, off);
            w3 += __shfl_xor(w3, off); w4 += __shfl_xor(w4, off);
            w5 += __shfl_xor(w5, off); w6 += __shfl_xor(w6, off);
            w7 += __shfl_xor(w7, off); w8 += __shfl_xor(w8, off);
        }
        den += w0;
        acc[0] += w1; acc[1] += w2; acc[2] += w3; acc[3] += w4;
        acc[4] += w5; acc[5] += w6; acc[6] += w7; acc[7] += w8;
    }
    if (lane == 0) {
        float inv = 1.0f / den;
        float o[8];
        #pragma unroll
        for (int cc = 0; cc < 8; ++cc) {
            float v = fmaf(acc[cc], inv, bias2[cc]);
            o[cc] = v > 0.0f ? v : expm1f(v);
        }
        *(float4*)(h2 + (size_t)node * 8)     = make_float4(o[0], o[1], o[2], o[3]);
        *(float4*)(h2 + (size_t)node * 8 + 4) = make_float4(o[4], o[5], o[6], o[7]);
    }
}

// One block per graph; batch is sorted -> binary-search the segment. No atomics.
// Fused mean + @W3 + b3.
__global__ void k_pool(const float* __restrict__ h2, const int* __restrict__ batch,
                       const float* __restrict__ W3, const float* __restrict__ b3,
                       float* __restrict__ out, int N) {
    int g = blockIdx.x;
    int lo = 0, hi = N;
    while (lo < hi) { int mid = (lo + hi) >> 1; if (batch[mid] < g) lo = mid + 1; else hi = mid; }
    int start = lo;
    int lo2 = start, hi2 = N;
    while (lo2 < hi2) { int mid = (lo2 + hi2) >> 1; if (batch[mid] < g + 1) lo2 = mid + 1; else hi2 = mid; }
    int end = lo2;
    int cnt = end - start;
    int t = threadIdx.x;
    int c = t & 7, rg = t >> 3;   // 32 row groups x 8 channels
    float s = 0.0f;
    for (int i = start + rg; i < end; i += 32) s += h2[(size_t)i * 8 + c];
    __shared__ float sm[256];
    sm[t] = s;
    __syncthreads();
    #pragma unroll
    for (int off = 16; off >= 1; off >>= 1) {
        if (rg < off) sm[t] += sm[t + off * 8];
        __syncthreads();
    }
    if (t == 0) {
        float inv = 1.0f / fmaxf((float)cnt, 1.0f);
        float acc = b3[0];
        #pragma unroll
        for (int cc = 0; cc < 8; ++cc) acc = fmaf(sm[cc] * inv, W3[cc], acc);
        out[g] = acc;
    }
}

extern "C" void kernel_launch(void* const* d_in, const int* in_sizes, int n_in,
                              void* d_out, int out_size, void* d_ws, size_t ws_size,
                              hipStream_t stream) {
    const float* x     = (const float*)d_in[0];
    const int*   ei    = (const int*)d_in[1];
    const float* ea    = (const float*)d_in[2];
    const int*   batch = (const int*)d_in[3];
    const float* Wl1 = (const float*)d_in[4];
    const float* bl1 = (const float*)d_in[5];
    const float* Wr1 = (const float*)d_in[6];
    const float* br1 = (const float*)d_in[7];
    const float* We1 = (const float*)d_in[8];
    const float* att1 = (const float*)d_in[9];
    const float* bias1 = (const float*)d_in[10];
    const float* Wl2 = (const float*)d_in[11];
    const float* bl2 = (const float*)d_in[12];
    const float* Wr2 = (const float*)d_in[13];
    const float* br2 = (const float*)d_in[14];
    const float* We2 = (const float*)d_in[15];
    const float* att2 = (const float*)d_in[16];
    const float* bias2 = (const float*)d_in[17];
    const float* W3 = (const float*)d_in[18];
    const float* b3 = (const float*)d_in[19];

    const int N  = in_sizes[0] / 4;
    const int E  = in_sizes[1] / 2;
    const int G  = out_size;
    const int* src = ei;
    const int* dst = ei + E;
    const int nb = (N + 255) / 256;   // <= 256 for N <= 65536

    float* w = (float*)d_ws;
    // Zone A: accumulators (memset to 0 every call)
    int*   degi   = (int*)w;  w += N;
    size_t zoneA_bytes = (size_t)((char*)w - (char*)d_ws);
    // Zone B: fully overwritten each call
    int*   row_ptr  = (int*)w; w += N + 1;
    int*   cursor   = (int*)w; w += N;
    int*   blocksum = (int*)w; w += 256;
    float* loop_ea  = w;       w += N;
    float* h1  = w;            w += (size_t)N * 128;
    float* xl2 = w;            w += (size_t)N * 8;
    float* xr2 = w;            w += (size_t)N * 8;
    int2*  csr = (int2*)w;     w += (size_t)E * 2;
    float* h2 = h1;            // h1 dead after k_l2_lin

    hipMemsetAsync(d_ws, 0, zoneA_bytes, stream);

    // CSR build
    k_hist<<<(E / 4 + 255) / 256, 256, 0, stream>>>(dst, degi, E);
    k_scan1<<<nb, 256, 0, stream>>>(degi, row_ptr, blocksum, N);
    k_scan2<<<1, 256, 0, stream>>>(blocksum, nb);
    k_scan3<<<nb, 256, 0, stream>>>(row_ptr, blocksum, cursor, N, E);
    k_scatter<<<(E + 255) / 256, 256, 0, stream>>>(src, dst, ea, cursor, csr, E);
    k_loopea<<<nb, 256, 0, stream>>>(row_ptr, csr, loop_ea, N);

    // layer 1
    k_l1_node<<<(N + 3) / 4, 256, 0, stream>>>(csr, row_ptr, x, loop_ea,
                                               Wl1, bl1, Wr1, br1, We1, att1, bias1, h1, N);
    // layer 2
    k_l2_lin<<<((size_t)N * 8 + 255) / 256, 256, 0, stream>>>(h1, Wl2, bl2, Wr2, br2,
                                                              xl2, xr2, N);
    k_l2_node<<<(N + 3) / 4, 256, 0, stream>>>(csr, row_ptr, xl2, xr2,
                                               loop_ea, We2, att2, bias2, h2, N);
    // pool + final linear
    k_pool<<<G, 256, 0, stream>>>(h2, batch, W3, b3, (float*)d_out, N);
}

// Round 7
// 222.941 us; speedup vs baseline: 1.2463x; 1.0674x over previous
//
#include <hip/hip_runtime.h>
#include <math.h>

#define LRELU(m) fmaxf((m), 0.2f * (m))
#define LOG2E 1.44269504088896340736f

// ---------------- CSR build ----------------

// in-degree histogram only (1 atomic per edge), x4 coarsened
__global__ void k_hist(const int* __restrict__ dst, int* __restrict__ degi, int E) {
    int e = (blockIdx.x * blockDim.x + threadIdx.x) * 4;
    if (e + 4 <= E) {
        int4 d4 = *(const int4*)(dst + e);
        atomicAdd(&degi[d4.x], 1);
        atomicAdd(&degi[d4.y], 1);
        atomicAdd(&degi[d4.z], 1);
        atomicAdd(&degi[d4.w], 1);
    } else {
        for (; e < E; ++e) atomicAdd(&degi[dst[e]], 1);
    }
}

__global__ void k_scan1(const int* __restrict__ degi, int* __restrict__ row_ptr,
                        int* __restrict__ blocksum, int N) {
    __shared__ int sm[256];
    int t = threadIdx.x;
    int i = blockIdx.x * 256 + t;
    int v = (i < N) ? degi[i] : 0;
    sm[t] = v;
    __syncthreads();
    #pragma unroll
    for (int off = 1; off < 256; off <<= 1) {
        int add = (t >= off) ? sm[t - off] : 0;
        __syncthreads();
        sm[t] += add;
        __syncthreads();
    }
    if (i < N) row_ptr[i] = sm[t] - v;   // exclusive
    if (t == 255) blocksum[blockIdx.x] = sm[255];
}

__global__ void k_scan2(int* __restrict__ blocksum, int nb) {
    __shared__ int sm[256];
    int t = threadIdx.x;
    int v = (t < nb) ? blocksum[t] : 0;
    sm[t] = v;
    __syncthreads();
    #pragma unroll
    for (int off = 1; off < 256; off <<= 1) {
        int add = (t >= off) ? sm[t - off] : 0;
        __syncthreads();
        sm[t] += add;
        __syncthreads();
    }
    if (t < nb) blocksum[t] = sm[t] - v;
}

__global__ void k_scan3(int* __restrict__ row_ptr, const int* __restrict__ blocksum,
                        int* __restrict__ cursor, int N, int E) {
    int i = blockIdx.x * 256 + threadIdx.x;
    if (i == 0) row_ptr[N] = E;
    if (i >= N) return;
    int r = row_ptr[i] + blocksum[blockIdx.x];
    row_ptr[i] = r;
    cursor[i] = r;
}

// scatter (src byte-offset of x-row, ea) as one packed 8B store per edge
__global__ void k_scatter(const int* __restrict__ src, const int* __restrict__ dst,
                          const float* __restrict__ ea, int* __restrict__ cursor,
                          int2* __restrict__ csr, int E) {
    int e = blockIdx.x * blockDim.x + threadIdx.x;
    if (e >= E) return;
    int d = dst[e];
    int pos = atomicAdd(&cursor[d], 1);
    csr[pos] = make_int2(src[e] * 16, __float_as_int(ea[e]));   // 16 B = one x row
}

// loop_ea[i] = (sum of incoming ea) / max(deg,1)  — contiguous segment read, no atomics
__global__ void k_loopea(const int* __restrict__ row_ptr, const int2* __restrict__ csr,
                         float* __restrict__ loop_ea, int N) {
    int i = blockIdx.x * blockDim.x + threadIdx.x;
    if (i >= N) return;
    int start = row_ptr[i], end = row_ptr[i + 1];
    float s = 0.0f;
    for (int k = start; k < end; ++k) s += __int_as_float(csr[k].y);
    loop_ea[i] = s / fmaxf((float)(end - start), 1.0f);
}

// ---------------- layer 1 ----------------

// One wave per dst node, lane = 2 channels. Gathers only x[s] (16 B broadcast);
// vl = Wl1^T x[s] + bl1 recomputed in-register. att pre-scaled by log2(e) -> exp2f.
__global__ void k_l1_node(const int2* __restrict__ csr, const int* __restrict__ row_ptr,
                          const float* __restrict__ x, const float* __restrict__ loop_ea,
                          const float* __restrict__ Wl1, const float* __restrict__ bl1,
                          const float* __restrict__ Wr1, const float* __restrict__ br1,
                          const float* __restrict__ We1, const float* __restrict__ att1,
                          const float* __restrict__ bias1, float* __restrict__ h1, int N) {
    int node = blockIdx.x * (blockDim.x >> 6) + (threadIdx.x >> 6);
    int lane = threadIdx.x & 63;
    if (node >= N) return;
    int c = lane * 2;
    float wl00 = Wl1[c],       wl01 = Wl1[c + 1];
    float wl10 = Wl1[128 + c], wl11 = Wl1[128 + c + 1];
    float wl20 = Wl1[256 + c], wl21 = Wl1[256 + c + 1];
    float wl30 = Wl1[384 + c], wl31 = Wl1[384 + c + 1];
    float b0 = bl1[c], b1 = bl1[c + 1];
    float4 xv = *(const float4*)(x + (size_t)node * 4);
    float r0 = br1[c], r1 = br1[c + 1];
    r0 = fmaf(xv.x, Wr1[c],       r0); r1 = fmaf(xv.x, Wr1[c + 1],       r1);
    r0 = fmaf(xv.y, Wr1[128 + c], r0); r1 = fmaf(xv.y, Wr1[128 + c + 1], r1);
    r0 = fmaf(xv.z, Wr1[256 + c], r0); r1 = fmaf(xv.z, Wr1[256 + c + 1], r1);
    r0 = fmaf(xv.w, Wr1[384 + c], r0); r1 = fmaf(xv.w, Wr1[384 + c + 1], r1);
    float2 we = *(const float2*)(We1 + c);
    float2 at = *(const float2*)(att1 + c);
    at.x *= LOG2E; at.y *= LOG2E;   // fold exp -> exp2
    const char* xb = (const char*)x;

    #define VL0(xs) fmaf((xs).w, wl30, fmaf((xs).z, wl20, fmaf((xs).y, wl10, fmaf((xs).x, wl00, b0))))
    #define VL1(xs) fmaf((xs).w, wl31, fmaf((xs).z, wl21, fmaf((xs).y, wl11, fmaf((xs).x, wl01, b1))))

    // self-loop
    float vx = VL0(xv), vy = VL1(xv);
    float eav = loop_ea[node];
    float p = LRELU(vx + r0 + eav * we.x) * at.x + LRELU(vy + r1 + eav * we.y) * at.y;
    p += __shfl_xor(p, 1); p += __shfl_xor(p, 2); p += __shfl_xor(p, 4);
    float a = exp2f(p);
    float den = a, accx = a * vx, accy = a * vy;
    int start = row_ptr[node], deg = row_ptr[node + 1] - start;
    int k = 0;
    for (; k + 4 <= deg; k += 4) {
        int2 pr0 = csr[start + k],     pr1 = csr[start + k + 1];
        int2 pr2 = csr[start + k + 2], pr3 = csr[start + k + 3];
        float e0 = __int_as_float(pr0.y), e1 = __int_as_float(pr1.y);
        float e2 = __int_as_float(pr2.y), e3 = __int_as_float(pr3.y);
        float4 x0 = *(const float4*)(xb + (unsigned)pr0.x);
        float4 x1 = *(const float4*)(xb + (unsigned)pr1.x);
        float4 x2 = *(const float4*)(xb + (unsigned)pr2.x);
        float4 x3 = *(const float4*)(xb + (unsigned)pr3.x);
        float v0x = VL0(x0), v0y = VL1(x0);
        float v1x = VL0(x1), v1y = VL1(x1);
        float v2x = VL0(x2), v2y = VL1(x2);
        float v3x = VL0(x3), v3y = VL1(x3);
        float p0 = LRELU(v0x + r0 + e0 * we.x) * at.x + LRELU(v0y + r1 + e0 * we.y) * at.y;
        float p1 = LRELU(v1x + r0 + e1 * we.x) * at.x + LRELU(v1y + r1 + e1 * we.y) * at.y;
        float p2 = LRELU(v2x + r0 + e2 * we.x) * at.x + LRELU(v2y + r1 + e2 * we.y) * at.y;
        float p3 = LRELU(v3x + r0 + e3 * we.x) * at.x + LRELU(v3y + r1 + e3 * we.y) * at.y;
        p0 += __shfl_xor(p0, 1); p1 += __shfl_xor(p1, 1); p2 += __shfl_xor(p2, 1); p3 += __shfl_xor(p3, 1);
        p0 += __shfl_xor(p0, 2); p1 += __shfl_xor(p1, 2); p2 += __shfl_xor(p2, 2); p3 += __shfl_xor(p3, 2);
        p0 += __shfl_xor(p0, 4); p1 += __shfl_xor(p1, 4); p2 += __shfl_xor(p2, 4); p3 += __shfl_xor(p3, 4);
        float a0 = exp2f(p0), a1 = exp2f(p1), a2 = exp2f(p2), a3 = exp2f(p3);
        den += (a0 + a1) + (a2 + a3);
        accx = fmaf(a0, v0x, accx); accy = fmaf(a0, v0y, accy);
        accx = fmaf(a1, v1x, accx); accy = fmaf(a1, v1y, accy);
        accx = fmaf(a2, v2x, accx); accy = fmaf(a2, v2y, accy);
        accx = fmaf(a3, v3x, accx); accy = fmaf(a3, v3y, accy);
    }
    for (; k < deg; ++k) {
        int2 pr = csr[start + k];
        float ee = __int_as_float(pr.y);
        float4 xs = *(const float4*)(xb + (unsigned)pr.x);
        float vsx = VL0(xs), vsy = VL1(xs);
        float pp = LRELU(vsx + r0 + ee * we.x) * at.x + LRELU(vsy + r1 + ee * we.y) * at.y;
        pp += __shfl_xor(pp, 1); pp += __shfl_xor(pp, 2); pp += __shfl_xor(pp, 4);
        float aa = exp2f(pp);
        den += aa;
        accx = fmaf(aa, vsx, accx);
        accy = fmaf(aa, vsy, accy);
    }
    #undef VL0
    #undef VL1
    float inv = 1.0f / den;
    float o0 = fmaf(accx, inv, bias1[c]);
    float o1 = fmaf(accy, inv, bias1[c + 1]);
    o0 = o0 > 0.0f ? o0 : expm1f(o0);
    o1 = o1 > 0.0f ? o1 : expm1f(o1);
    *(float2*)(h1 + (size_t)node * 128 + c) = make_float2(o0, o1);
}

// ---------------- layer 2 ----------------

// thread = (node, j): computes xl2 and xr2 together with float4 row loads
__global__ void k_l2_lin(const float* __restrict__ h1, const float* __restrict__ Wl2,
                         const float* __restrict__ bl2, const float* __restrict__ Wr2,
                         const float* __restrict__ br2, float* __restrict__ xl2,
                         float* __restrict__ xr2, int N) {
    int t = blockIdx.x * blockDim.x + threadIdx.x;
    if (t >= N * 8) return;
    int i = t >> 3, j = t & 7;
    float accl = bl2[j], accr = br2[j];
    const float* row = h1 + (size_t)i * 128;
    #pragma unroll 4
    for (int k = 0; k < 128; k += 4) {
        float4 hv = *(const float4*)(row + k);
        accl = fmaf(hv.x, Wl2[k * 8 + j], accl);       accr = fmaf(hv.x, Wr2[k * 8 + j], accr);
        accl = fmaf(hv.y, Wl2[(k + 1) * 8 + j], accl); accr = fmaf(hv.y, Wr2[(k + 1) * 8 + j], accr);
        accl = fmaf(hv.z, Wl2[(k + 2) * 8 + j], accl); accr = fmaf(hv.z, Wr2[(k + 2) * 8 + j], accr);
        accl = fmaf(hv.w, Wl2[(k + 3) * 8 + j], accl); accr = fmaf(hv.w, Wr2[(k + 3) * 8 + j], accr);
    }
    xl2[t] = accl;
    xr2[t] = accr;
}

// 8 lanes per dst node (8 nodes per wave), lane = edge within group.
// 3-step butterfly within the 8-lane group. No atomics: writes h2 coalesced.
__global__ void k_l2_node(const int2* __restrict__ csr, const int* __restrict__ row_ptr,
                          const float* __restrict__ xl2, const float* __restrict__ xr2,
                          const float* __restrict__ loop_ea,
                          const float* __restrict__ We2, const float* __restrict__ att2,
                          const float* __restrict__ bias2, float* __restrict__ h2, int N) {
    int t = blockIdx.x * blockDim.x + threadIdx.x;
    int node = t >> 3;
    int lane = t & 7;
    if (node >= N) return;
    float4 ra = *(const float4*)(xr2 + (size_t)node * 8);
    float4 rb = *(const float4*)(xr2 + (size_t)node * 8 + 4);
    float r[8] = {ra.x, ra.y, ra.z, ra.w, rb.x, rb.y, rb.z, rb.w};
    float we[8], at[8];
    #pragma unroll
    for (int cc = 0; cc < 8; ++cc) { we[cc] = We2[cc]; at[cc] = att2[cc] * LOG2E; }
    const char* xlb = (const char*)xl2;
    int start = row_ptr[node], deg = row_ptr[node + 1] - start;
    int total = deg + 1;          // + self loop
    float den = 0.0f;
    float acc[8];
    #pragma unroll
    for (int cc = 0; cc < 8; ++cc) acc[cc] = 0.0f;
    for (int base = 0; base < total; base += 8) {
        int e = base + lane;
        float a = 0.0f;
        float l[8];
        #pragma unroll
        for (int cc = 0; cc < 8; ++cc) l[cc] = 0.0f;
        if (e < total) {
            const float* lp;
            float eav;
            if (e < deg) {
                int2 pr = csr[start + e];
                lp = (const float*)(xlb + 2u * (unsigned)pr.x);   // src*32 bytes
                eav = __int_as_float(pr.y);
            } else {
                lp = xl2 + (size_t)node * 8;
                eav = loop_ea[node];
            }
            float4 la = *(const float4*)lp;
            float4 lb = *(const float4*)(lp + 4);
            l[0] = la.x; l[1] = la.y; l[2] = la.z; l[3] = la.w;
            l[4] = lb.x; l[5] = lb.y; l[6] = lb.z; l[7] = lb.w;
            float p = 0.0f;
            #pragma unroll
            for (int cc = 0; cc < 8; ++cc) {
                float m = l[cc] + r[cc] + eav * we[cc];
                p = fmaf(LRELU(m), at[cc], p);
            }
            a = exp2f(p);
        }
        float w0 = a;
        float w1 = a * l[0], w2 = a * l[1], w3 = a * l[2], w4 = a * l[3];
        float w5 = a * l[4], w6 = a * l[5], w7 = a * l[6], w8 = a * l[7];
        #pragma unroll
        for (int off = 1; off < 8; off <<= 1) {
            w0 += __shfl_xor(w0, off);
            w1 += __shfl_xor(w1, off); w2 += __shfl_xor(w2, off);
            w3 += __shfl_xor(w3, off); w4 += __shfl_xor(w4, off);
            w5 += __shfl_xor(w5, off); w6 += __shfl_xor(w6, off);
            w7 += __shfl_xor(w7, off); w8 += __shfl_xor(w8, off);
        }
        den += w0;
        acc[0] += w1; acc[1] += w2; acc[2] += w3; acc[3] += w4;
        acc[4] += w5; acc[5] += w6; acc[6] += w7; acc[7] += w8;
    }
    if (lane == 0) {
        float inv = 1.0f / den;
        float o[8];
        #pragma unroll
        for (int cc = 0; cc < 8; ++cc) {
            float v = fmaf(acc[cc], inv, bias2[cc]);
            o[cc] = v > 0.0f ? v : expm1f(v);
        }
        *(float4*)(h2 + (size_t)node * 8)     = make_float4(o[0], o[1], o[2], o[3]);
        *(float4*)(h2 + (size_t)node * 8 + 4) = make_float4(o[4], o[5], o[6], o[7]);
    }
}

// One block per graph; batch is sorted -> binary-search the segment. No atomics.
// Fused mean + @W3 + b3.
__global__ void k_pool(const float* __restrict__ h2, const int* __restrict__ batch,
                       const float* __restrict__ W3, const float* __restrict__ b3,
                       float* __restrict__ out, int N) {
    int g = blockIdx.x;
    int lo = 0, hi = N;
    while (lo < hi) { int mid = (lo + hi) >> 1; if (batch[mid] < g) lo = mid + 1; else hi = mid; }
    int start = lo;
    int lo2 = start, hi2 = N;
    while (lo2 < hi2) { int mid = (lo2 + hi2) >> 1; if (batch[mid] < g + 1) lo2 = mid + 1; else hi2 = mid; }
    int end = lo2;
    int cnt = end - start;
    int t = threadIdx.x;
    int c = t & 7, rg = t >> 3;   // 32 row groups x 8 channels
    float s = 0.0f;
    for (int i = start + rg; i < end; i += 32) s += h2[(size_t)i * 8 + c];
    __shared__ float sm[256];
    sm[t] = s;
    __syncthreads();
    #pragma unroll
    for (int off = 16; off >= 1; off >>= 1) {
        if (rg < off) sm[t] += sm[t + off * 8];
        __syncthreads();
    }
    if (t == 0) {
        float inv = 1.0f / fmaxf((float)cnt, 1.0f);
        float acc = b3[0];
        #pragma unroll
        for (int cc = 0; cc < 8; ++cc) acc = fmaf(sm[cc] * inv, W3[cc], acc);
        out[g] = acc;
    }
}

extern "C" void kernel_launch(void* const* d_in, const int* in_sizes, int n_in,
                              void* d_out, int out_size, void* d_ws, size_t ws_size,
                              hipStream_t stream) {
    const float* x     = (const float*)d_in[0];
    const int*   ei    = (const int*)d_in[1];
    const float* ea    = (const float*)d_in[2];
    const int*   batch = (const int*)d_in[3];
    const float* Wl1 = (const float*)d_in[4];
    const float* bl1 = (const float*)d_in[5];
    const float* Wr1 = (const float*)d_in[6];
    const float* br1 = (const float*)d_in[7];
    const float* We1 = (const float*)d_in[8];
    const float* att1 = (const float*)d_in[9];
    const float* bias1 = (const float*)d_in[10];
    const float* Wl2 = (const float*)d_in[11];
    const float* bl2 = (const float*)d_in[12];
    const float* Wr2 = (const float*)d_in[13];
    const float* br2 = (const float*)d_in[14];
    const float* We2 = (const float*)d_in[15];
    const float* att2 = (const float*)d_in[16];
    const float* bias2 = (const float*)d_in[17];
    const float* W3 = (const float*)d_in[18];
    const float* b3 = (const float*)d_in[19];

    const int N  = in_sizes[0] / 4;
    const int E  = in_sizes[1] / 2;
    const int G  = out_size;
    const int* src = ei;
    const int* dst = ei + E;
    const int nb = (N + 255) / 256;   // <= 256 for N <= 65536

    float* w = (float*)d_ws;
    // Zone A: accumulators (memset to 0 every call)
    int*   degi   = (int*)w;  w += N;
    size_t zoneA_bytes = (size_t)((char*)w - (char*)d_ws);
    // Zone B: fully overwritten each call
    int*   row_ptr  = (int*)w; w += N + 1;
    int*   cursor   = (int*)w; w += N;
    int*   blocksum = (int*)w; w += 256;
    float* loop_ea  = w;       w += N;
    float* h1  = w;            w += (size_t)N * 128;
    float* xl2 = w;            w += (size_t)N * 8;
    float* xr2 = w;            w += (size_t)N * 8;
    int2*  csr = (int2*)w;     w += (size_t)E * 2;
    float* h2 = h1;            // h1 dead after k_l2_lin

    hipMemsetAsync(d_ws, 0, zoneA_bytes, stream);

    // CSR build
    k_hist<<<(E / 4 + 255) / 256, 256, 0, stream>>>(dst, degi, E);
    k_scan1<<<nb, 256, 0, stream>>>(degi, row_ptr, blocksum, N);
    k_scan2<<<1, 256, 0, stream>>>(blocksum, nb);
    k_scan3<<<nb, 256, 0, stream>>>(row_ptr, blocksum, cursor, N, E);
    k_scatter<<<(E + 255) / 256, 256, 0, stream>>>(src, dst, ea, cursor, csr, E);
    k_loopea<<<nb, 256, 0, stream>>>(row_ptr, csr, loop_ea, N);

    // layer 1
    k_l1_node<<<(N + 3) / 4, 256, 0, stream>>>(csr, row_ptr, x, loop_ea,
                                               Wl1, bl1, Wr1, br1, We1, att1, bias1, h1, N);
    // layer 2
    k_l2_lin<<<((size_t)N * 8 + 255) / 256, 256, 0, stream>>>(h1, Wl2, bl2, Wr2, br2,
                                                              xl2, xr2, N);
    k_l2_node<<<((size_t)N * 8 + 255) / 256, 256, 0, stream>>>(csr, row_ptr, xl2, xr2,
                                                               loop_ea, We2, att2, bias2, h2, N);
    // pool + final linear
    k_pool<<<G, 256, 0, stream>>>(h2, batch, W3, b3, (float*)d_out, N);
}

// Round 8
// 210.275 us; speedup vs baseline: 1.3214x; 1.0602x over previous
//
#include <hip/hip_runtime.h>
#include <math.h>

#define LRELU(m) fmaxf((m), 0.2f * (m))
#define LOG2E 1.44269504088896340736f

// butterfly add via DPP (pure VALU, no LDS): xor1=quad_perm[1,0,3,2],
// xor2=quad_perm[2,3,0,1], "xor4" pairing = row_half_mirror (valid within 8-lane groups)
#define DPPADD(p, ctrl) \
    p += __int_as_float(__builtin_amdgcn_mov_dpp(__float_as_int(p), ctrl, 0xF, 0xF, true))
#define RED8(p) do { DPPADD(p, 0xB1); DPPADD(p, 0x4E); DPPADD(p, 0x141); } while (0)

// ---------------- CSR build ----------------

// in-degree histogram only (1 atomic per edge), x4 coarsened
__global__ void k_hist(const int* __restrict__ dst, int* __restrict__ degi, int E) {
    int e = (blockIdx.x * blockDim.x + threadIdx.x) * 4;
    if (e + 4 <= E) {
        int4 d4 = *(const int4*)(dst + e);
        atomicAdd(&degi[d4.x], 1);
        atomicAdd(&degi[d4.y], 1);
        atomicAdd(&degi[d4.z], 1);
        atomicAdd(&degi[d4.w], 1);
    } else {
        for (; e < E; ++e) atomicAdd(&degi[dst[e]], 1);
    }
}

__global__ void k_scan1(const int* __restrict__ degi, int* __restrict__ row_ptr,
                        int* __restrict__ blocksum, int N) {
    __shared__ int sm[256];
    int t = threadIdx.x;
    int i = blockIdx.x * 256 + t;
    int v = (i < N) ? degi[i] : 0;
    sm[t] = v;
    __syncthreads();
    #pragma unroll
    for (int off = 1; off < 256; off <<= 1) {
        int add = (t >= off) ? sm[t - off] : 0;
        __syncthreads();
        sm[t] += add;
        __syncthreads();
    }
    if (i < N) row_ptr[i] = sm[t] - v;   // exclusive
    if (t == 255) blocksum[blockIdx.x] = sm[255];
}

__global__ void k_scan2(int* __restrict__ blocksum, int nb) {
    __shared__ int sm[256];
    int t = threadIdx.x;
    int v = (t < nb) ? blocksum[t] : 0;
    sm[t] = v;
    __syncthreads();
    #pragma unroll
    for (int off = 1; off < 256; off <<= 1) {
        int add = (t >= off) ? sm[t - off] : 0;
        __syncthreads();
        sm[t] += add;
        __syncthreads();
    }
    if (t < nb) blocksum[t] = sm[t] - v;
}

__global__ void k_scan3(int* __restrict__ row_ptr, const int* __restrict__ blocksum,
                        int* __restrict__ cursor, int N, int E) {
    int i = blockIdx.x * 256 + threadIdx.x;
    if (i == 0) row_ptr[N] = E;
    if (i >= N) return;
    int r = row_ptr[i] + blocksum[blockIdx.x];
    row_ptr[i] = r;
    cursor[i] = r;
}

// scatter (src byte-offset of x-row, ea) as one packed 8B store per edge; x4 coarsened
__global__ void k_scatter(const int* __restrict__ src, const int* __restrict__ dst,
                          const float* __restrict__ ea, int* __restrict__ cursor,
                          int2* __restrict__ csr, int E) {
    int e = (blockIdx.x * blockDim.x + threadIdx.x) * 4;
    if (e + 4 <= E) {
        int4 s4 = *(const int4*)(src + e);
        int4 d4 = *(const int4*)(dst + e);
        float4 a4 = *(const float4*)(ea + e);
        int p0 = atomicAdd(&cursor[d4.x], 1);
        int p1 = atomicAdd(&cursor[d4.y], 1);
        int p2 = atomicAdd(&cursor[d4.z], 1);
        int p3 = atomicAdd(&cursor[d4.w], 1);
        csr[p0] = make_int2(s4.x * 16, __float_as_int(a4.x));
        csr[p1] = make_int2(s4.y * 16, __float_as_int(a4.y));
        csr[p2] = make_int2(s4.z * 16, __float_as_int(a4.z));
        csr[p3] = make_int2(s4.w * 16, __float_as_int(a4.w));
    } else {
        for (; e < E; ++e) {
            int pos = atomicAdd(&cursor[dst[e]], 1);
            csr[pos] = make_int2(src[e] * 16, __float_as_int(ea[e]));
        }
    }
}

// loop_ea[i] = (sum of incoming ea) / max(deg,1)
__global__ void k_loopea(const int* __restrict__ row_ptr, const int2* __restrict__ csr,
                         float* __restrict__ loop_ea, int N) {
    int i = blockIdx.x * blockDim.x + threadIdx.x;
    if (i >= N) return;
    int start = row_ptr[i], end = row_ptr[i + 1];
    float s = 0.0f;
    for (int k = start; k < end; ++k) s += __int_as_float(csr[k].y);
    loop_ea[i] = s / fmaxf((float)(end - start), 1.0f);
}

// ---------------- layer 1 ----------------

// One wave per dst node, lane = 2 channels. node forced wave-uniform via
// readfirstlane -> all inner-loop loads (csr pairs, 16B x rows) become scalar
// s_loads; inner loop has zero vector-memory ops. Head-reduce via DPP (no LDS).
__global__ void k_l1_node(const int2* __restrict__ csr, const int* __restrict__ row_ptr,
                          const float* __restrict__ x, const float* __restrict__ loop_ea,
                          const float* __restrict__ Wl1, const float* __restrict__ bl1,
                          const float* __restrict__ Wr1, const float* __restrict__ br1,
                          const float* __restrict__ We1, const float* __restrict__ att1,
                          const float* __restrict__ bias1, float* __restrict__ h1, int N) {
    int node = blockIdx.x * (blockDim.x >> 6) + (threadIdx.x >> 6);
    if (node >= N) return;
    node = __builtin_amdgcn_readfirstlane(node);
    int lane = threadIdx.x & 63;
    int c = lane * 2;
    float wl00 = Wl1[c],       wl01 = Wl1[c + 1];
    float wl10 = Wl1[128 + c], wl11 = Wl1[128 + c + 1];
    float wl20 = Wl1[256 + c], wl21 = Wl1[256 + c + 1];
    float wl30 = Wl1[384 + c], wl31 = Wl1[384 + c + 1];
    float b0 = bl1[c], b1 = bl1[c + 1];
    float4 xv = *(const float4*)(x + (size_t)node * 4);
    float r0 = br1[c], r1 = br1[c + 1];
    r0 = fmaf(xv.x, Wr1[c],       r0); r1 = fmaf(xv.x, Wr1[c + 1],       r1);
    r0 = fmaf(xv.y, Wr1[128 + c], r0); r1 = fmaf(xv.y, Wr1[128 + c + 1], r1);
    r0 = fmaf(xv.z, Wr1[256 + c], r0); r1 = fmaf(xv.z, Wr1[256 + c + 1], r1);
    r0 = fmaf(xv.w, Wr1[384 + c], r0); r1 = fmaf(xv.w, Wr1[384 + c + 1], r1);
    float2 we = *(const float2*)(We1 + c);
    float2 at = *(const float2*)(att1 + c);
    at.x *= LOG2E; at.y *= LOG2E;   // fold exp -> exp2
    const char* xb = (const char*)x;

    #define VL0(xs) fmaf((xs).w, wl30, fmaf((xs).z, wl20, fmaf((xs).y, wl10, fmaf((xs).x, wl00, b0))))
    #define VL1(xs) fmaf((xs).w, wl31, fmaf((xs).z, wl21, fmaf((xs).y, wl11, fmaf((xs).x, wl01, b1))))

    int start = row_ptr[node];
    int deg   = row_ptr[node + 1] - start;
    const int2* crow = csr + start;

    // self-loop
    float vx = VL0(xv), vy = VL1(xv);
    float eav = loop_ea[node];
    float p = LRELU(vx + r0 + eav * we.x) * at.x + LRELU(vy + r1 + eav * we.y) * at.y;
    RED8(p);
    float a = exp2f(p);
    float den = a, accx = a * vx, accy = a * vy;
    int k = 0;
    for (; k + 4 <= deg; k += 4) {
        int2 pr0 = crow[k],     pr1 = crow[k + 1];
        int2 pr2 = crow[k + 2], pr3 = crow[k + 3];
        float e0 = __int_as_float(pr0.y), e1 = __int_as_float(pr1.y);
        float e2 = __int_as_float(pr2.y), e3 = __int_as_float(pr3.y);
        float4 x0 = *(const float4*)(xb + (unsigned)pr0.x);
        float4 x1 = *(const float4*)(xb + (unsigned)pr1.x);
        float4 x2 = *(const float4*)(xb + (unsigned)pr2.x);
        float4 x3 = *(const float4*)(xb + (unsigned)pr3.x);
        float v0x = VL0(x0), v0y = VL1(x0);
        float v1x = VL0(x1), v1y = VL1(x1);
        float v2x = VL0(x2), v2y = VL1(x2);
        float v3x = VL0(x3), v3y = VL1(x3);
        float p0 = LRELU(v0x + r0 + e0 * we.x) * at.x + LRELU(v0y + r1 + e0 * we.y) * at.y;
        float p1 = LRELU(v1x + r0 + e1 * we.x) * at.x + LRELU(v1y + r1 + e1 * we.y) * at.y;
        float p2 = LRELU(v2x + r0 + e2 * we.x) * at.x + LRELU(v2y + r1 + e2 * we.y) * at.y;
        float p3 = LRELU(v3x + r0 + e3 * we.x) * at.x + LRELU(v3y + r1 + e3 * we.y) * at.y;
        RED8(p0); RED8(p1); RED8(p2); RED8(p3);
        float a0 = exp2f(p0), a1 = exp2f(p1), a2 = exp2f(p2), a3 = exp2f(p3);
        den += (a0 + a1) + (a2 + a3);
        accx = fmaf(a0, v0x, accx); accy = fmaf(a0, v0y, accy);
        accx = fmaf(a1, v1x, accx); accy = fmaf(a1, v1y, accy);
        accx = fmaf(a2, v2x, accx); accy = fmaf(a2, v2y, accy);
        accx = fmaf(a3, v3x, accx); accy = fmaf(a3, v3y, accy);
    }
    for (; k < deg; ++k) {
        int2 pr = crow[k];
        float ee = __int_as_float(pr.y);
        float4 xs = *(const float4*)(xb + (unsigned)pr.x);
        float vsx = VL0(xs), vsy = VL1(xs);
        float pp = LRELU(vsx + r0 + ee * we.x) * at.x + LRELU(vsy + r1 + ee * we.y) * at.y;
        RED8(pp);
        float aa = exp2f(pp);
        den += aa;
        accx = fmaf(aa, vsx, accx);
        accy = fmaf(aa, vsy, accy);
    }
    #undef VL0
    #undef VL1
    float inv = 1.0f / den;
    float o0 = fmaf(accx, inv, bias1[c]);
    float o1 = fmaf(accy, inv, bias1[c + 1]);
    o0 = o0 > 0.0f ? o0 : expm1f(o0);
    o1 = o1 > 0.0f ? o1 : expm1f(o1);
    *(float2*)(h1 + (size_t)node * 128 + c) = make_float2(o0, o1);
}

// ---------------- layer 2 ----------------

// thread = (node, j): computes xl2 and xr2 together with float4 row loads
__global__ void k_l2_lin(const float* __restrict__ h1, const float* __restrict__ Wl2,
                         const float* __restrict__ bl2, const float* __restrict__ Wr2,
                         const float* __restrict__ br2, float* __restrict__ xl2,
                         float* __restrict__ xr2, int N) {
    int t = blockIdx.x * blockDim.x + threadIdx.x;
    if (t >= N * 8) return;
    int i = t >> 3, j = t & 7;
    float accl = bl2[j], accr = br2[j];
    const float* row = h1 + (size_t)i * 128;
    #pragma unroll 4
    for (int k = 0; k < 128; k += 4) {
        float4 hv = *(const float4*)(row + k);
        accl = fmaf(hv.x, Wl2[k * 8 + j], accl);       accr = fmaf(hv.x, Wr2[k * 8 + j], accr);
        accl = fmaf(hv.y, Wl2[(k + 1) * 8 + j], accl); accr = fmaf(hv.y, Wr2[(k + 1) * 8 + j], accr);
        accl = fmaf(hv.z, Wl2[(k + 2) * 8 + j], accl); accr = fmaf(hv.z, Wr2[(k + 2) * 8 + j], accr);
        accl = fmaf(hv.w, Wl2[(k + 3) * 8 + j], accl); accr = fmaf(hv.w, Wr2[(k + 3) * 8 + j], accr);
    }
    xl2[t] = accl;
    xr2[t] = accr;
}

// 8 lanes per dst node (8 nodes per wave), lane = edge within group.
// 3-step DPP butterfly within the 8-lane group. No atomics.
__global__ void k_l2_node(const int2* __restrict__ csr, const int* __restrict__ row_ptr,
                          const float* __restrict__ xl2, const float* __restrict__ xr2,
                          const float* __restrict__ loop_ea,
                          const float* __restrict__ We2, const float* __restrict__ att2,
                          const float* __restrict__ bias2, float* __restrict__ h2, int N) {
    int t = blockIdx.x * blockDim.x + threadIdx.x;
    int node = t >> 3;
    int lane = t & 7;
    if (node >= N) return;
    float4 ra = *(const float4*)(xr2 + (size_t)node * 8);
    float4 rb = *(const float4*)(xr2 + (size_t)node * 8 + 4);
    float r[8] = {ra.x, ra.y, ra.z, ra.w, rb.x, rb.y, rb.z, rb.w};
    float we[8], at[8];
    #pragma unroll
    for (int cc = 0; cc < 8; ++cc) { we[cc] = We2[cc]; at[cc] = att2[cc] * LOG2E; }
    const char* xlb = (const char*)xl2;
    int start = row_ptr[node], deg = row_ptr[node + 1] - start;
    int total = deg + 1;          // + self loop
    float den = 0.0f;
    float acc[8];
    #pragma unroll
    for (int cc = 0; cc < 8; ++cc) acc[cc] = 0.0f;
    for (int base = 0; base < total; base += 8) {
        int e = base + lane;
        float a = 0.0f;
        float l[8];
        #pragma unroll
        for (int cc = 0; cc < 8; ++cc) l[cc] = 0.0f;
        if (e < total) {
            const float* lp;
            float eav;
            if (e < deg) {
                int2 pr = csr[start + e];
                lp = (const float*)(xlb + 2u * (unsigned)pr.x);   // src*32 bytes
                eav = __int_as_float(pr.y);
            } else {
                lp = xl2 + (size_t)node * 8;
                eav = loop_ea[node];
            }
            float4 la = *(const float4*)lp;
            float4 lb = *(const float4*)(lp + 4);
            l[0] = la.x; l[1] = la.y; l[2] = la.z; l[3] = la.w;
            l[4] = lb.x; l[5] = lb.y; l[6] = lb.z; l[7] = lb.w;
            float p = 0.0f;
            #pragma unroll
            for (int cc = 0; cc < 8; ++cc) {
                float m = l[cc] + r[cc] + eav * we[cc];
                p = fmaf(LRELU(m), at[cc], p);
            }
            a = exp2f(p);
        }
        float w0 = a;
        float w1 = a * l[0], w2 = a * l[1], w3 = a * l[2], w4 = a * l[3];
        float w5 = a * l[4], w6 = a * l[5], w7 = a * l[6], w8 = a * l[7];
        RED8(w0);
        RED8(w1); RED8(w2); RED8(w3); RED8(w4);
        RED8(w5); RED8(w6); RED8(w7); RED8(w8);
        den += w0;
        acc[0] += w1; acc[1] += w2; acc[2] += w3; acc[3] += w4;
        acc[4] += w5; acc[5] += w6; acc[6] += w7; acc[7] += w8;
    }
    if (lane == 0) {
        float inv = 1.0f / den;
        float o[8];
        #pragma unroll
        for (int cc = 0; cc < 8; ++cc) {
            float v = fmaf(acc[cc], inv, bias2[cc]);
            o[cc] = v > 0.0f ? v : expm1f(v);
        }
        *(float4*)(h2 + (size_t)node * 8)     = make_float4(o[0], o[1], o[2], o[3]);
        *(float4*)(h2 + (size_t)node * 8 + 4) = make_float4(o[4], o[5], o[6], o[7]);
    }
}

// One block per graph; batch is sorted -> binary-search the segment. No atomics.
// Fused mean + @W3 + b3.
__global__ void k_pool(const float* __restrict__ h2, const int* __restrict__ batch,
                       const float* __restrict__ W3, const float* __restrict__ b3,
                       float* __restrict__ out, int N) {
    int g = blockIdx.x;
    int lo = 0, hi = N;
    while (lo < hi) { int mid = (lo + hi) >> 1; if (batch[mid] < g) lo = mid + 1; else hi = mid; }
    int start = lo;
    int lo2 = start, hi2 = N;
    while (lo2 < hi2) { int mid = (lo2 + hi2) >> 1; if (batch[mid] < g + 1) lo2 = mid + 1; else hi2 = mid; }
    int end = lo2;
    int cnt = end - start;
    int t = threadIdx.x;
    int c = t & 7, rg = t >> 3;   // 32 row groups x 8 channels
    float s = 0.0f;
    for (int i = start + rg; i < end; i += 32) s += h2[(size_t)i * 8 + c];
    __shared__ float sm[256];
    sm[t] = s;
    __syncthreads();
    #pragma unroll
    for (int off = 16; off >= 1; off >>= 1) {
        if (rg < off) sm[t] += sm[t + off * 8];
        __syncthreads();
    }
    if (t == 0) {
        float inv = 1.0f / fmaxf((float)cnt, 1.0f);
        float acc = b3[0];
        #pragma unroll
        for (int cc = 0; cc < 8; ++cc) acc = fmaf(sm[cc] * inv, W3[cc], acc);
        out[g] = acc;
    }
}

extern "C" void kernel_launch(void* const* d_in, const int* in_sizes, int n_in,
                              void* d_out, int out_size, void* d_ws, size_t ws_size,
                              hipStream_t stream) {
    const float* x     = (const float*)d_in[0];
    const int*   ei    = (const int*)d_in[1];
    const float* ea    = (const float*)d_in[2];
    const int*   batch = (const int*)d_in[3];
    const float* Wl1 = (const float*)d_in[4];
    const float* bl1 = (const float*)d_in[5];
    const float* Wr1 = (const float*)d_in[6];
    const float* br1 = (const float*)d_in[7];
    const float* We1 = (const float*)d_in[8];
    const float* att1 = (const float*)d_in[9];
    const float* bias1 = (const float*)d_in[10];
    const float* Wl2 = (const float*)d_in[11];
    const float* bl2 = (const float*)d_in[12];
    const float* Wr2 = (const float*)d_in[13];
    const float* br2 = (const float*)d_in[14];
    const float* We2 = (const float*)d_in[15];
    const float* att2 = (const float*)d_in[16];
    const float* bias2 = (const float*)d_in[17];
    const float* W3 = (const float*)d_in[18];
    const float* b3 = (const float*)d_in[19];

    const int N  = in_sizes[0] / 4;
    const int E  = in_sizes[1] / 2;
    const int G  = out_size;
    const int* src = ei;
    const int* dst = ei + E;
    const int nb = (N + 255) / 256;   // <= 256 for N <= 65536

    float* w = (float*)d_ws;
    // Zone A: accumulators (memset to 0 every call)
    int*   degi   = (int*)w;  w += N;
    size_t zoneA_bytes = (size_t)((char*)w - (char*)d_ws);
    // Zone B: fully overwritten each call
    int*   row_ptr  = (int*)w; w += N + 1;
    int*   cursor   = (int*)w; w += N;
    int*   blocksum = (int*)w; w += 256;
    float* loop_ea  = w;       w += N;
    float* h1  = w;            w += (size_t)N * 128;
    float* xl2 = w;            w += (size_t)N * 8;
    float* xr2 = w;            w += (size_t)N * 8;
    int2*  csr = (int2*)w;     w += (size_t)E * 2;
    float* h2 = h1;            // h1 dead after k_l2_lin

    hipMemsetAsync(d_ws, 0, zoneA_bytes, stream);

    // CSR build
    k_hist<<<(E / 4 + 255) / 256, 256, 0, stream>>>(dst, degi, E);
    k_scan1<<<nb, 256, 0, stream>>>(degi, row_ptr, blocksum, N);
    k_scan2<<<1, 256, 0, stream>>>(blocksum, nb);
    k_scan3<<<nb, 256, 0, stream>>>(row_ptr, blocksum, cursor, N, E);
    k_scatter<<<(E / 4 + 255) / 256, 256, 0, stream>>>(src, dst, ea, cursor, csr, E);
    k_loopea<<<nb, 256, 0, stream>>>(row_ptr, csr, loop_ea, N);

    // layer 1
    k_l1_node<<<(N + 3) / 4, 256, 0, stream>>>(csr, row_ptr, x, loop_ea,
                                               Wl1, bl1, Wr1, br1, We1, att1, bias1, h1, N);
    // layer 2
    k_l2_lin<<<((size_t)N * 8 + 255) / 256, 256, 0, stream>>>(h1, Wl2, bl2, Wr2, br2,
                                                              xl2, xr2, N);
    k_l2_node<<<((size_t)N * 8 + 255) / 256, 256, 0, stream>>>(csr, row_ptr, xl2, xr2,
                                                               loop_ea, We2, att2, bias2, h2, N);
    // pool + final linear
    k_pool<<<G, 256, 0, stream>>>(h2, batch, W3, b3, (float*)d_out, N);
}

// Round 9
// 140.599 us; speedup vs baseline: 1.9762x; 1.4956x over previous
//
#include <hip/hip_runtime.h>
#include <math.h>

#define LRELU(m) fmaxf((m), 0.2f * (m))
#define LOG2E 1.44269504088896340736f

// butterfly add via DPP (pure VALU, no LDS): xor1=quad_perm[1,0,3,2],
// xor2=quad_perm[2,3,0,1], "xor4" pairing = row_half_mirror (valid within 8-lane groups)
#define DPPADD(p, ctrl) \
    p += __int_as_float(__builtin_amdgcn_mov_dpp(__float_as_int(p), ctrl, 0xF, 0xF, true))
#define RED8(p) do { DPPADD(p, 0xB1); DPPADD(p, 0x4E); DPPADD(p, 0x141); } while (0)

// ---------------- CSR build: two-level counting sort (no global atomics) ----
// bucket = dst >> 8 (256 nodes per bucket), NBK = ceil(N/256) <= 256
// chunks: NCH = 256 edge chunks, CE = ceil(E/NCH) edges each
// packed tmp entry: ( (dst&255)<<24 | (src*16), ea_bits )

// Pass A: per-chunk bucket histogram -> cnt[bkt * 256 + chunk]
__global__ void k_bcnt(const int* __restrict__ dst, int* __restrict__ cntmat,
                       int E, int CE, int NBK) {
    __shared__ int cnt[256];
    int t = threadIdx.x;
    cnt[t] = 0;
    __syncthreads();
    int c = blockIdx.x;
    int lo = c * CE, hi = min(E, lo + CE);
    for (int e = lo + t; e < hi; e += 256)
        atomicAdd(&cnt[dst[e] >> 8], 1);
    __syncthreads();
    if (t < NBK) cntmat[t * 256 + c] = cnt[t];
}

// per-block exclusive scan (in-place safe: reads to LDS first)
__global__ void k_scan1(const int* __restrict__ in, int* __restrict__ out,
                        int* __restrict__ blocksum, int L) {
    __shared__ int sm[256];
    int t = threadIdx.x;
    int i = blockIdx.x * 256 + t;
    int v = (i < L) ? in[i] : 0;
    sm[t] = v;
    __syncthreads();
    #pragma unroll
    for (int off = 1; off < 256; off <<= 1) {
        int add = (t >= off) ? sm[t - off] : 0;
        __syncthreads();
        sm[t] += add;
        __syncthreads();
    }
    if (i < L) out[i] = sm[t] - v;   // exclusive
    if (t == 255) blocksum[blockIdx.x] = sm[255];
}

__global__ void k_scan2(int* __restrict__ blocksum, int nb) {
    __shared__ int sm[256];
    int t = threadIdx.x;
    int v = (t < nb) ? blocksum[t] : 0;
    sm[t] = v;
    __syncthreads();
    #pragma unroll
    for (int off = 1; off < 256; off <<= 1) {
        int add = (t >= off) ? sm[t - off] : 0;
        __syncthreads();
        sm[t] += add;
        __syncthreads();
    }
    if (t < nb) blocksum[t] = sm[t] - v;
}

__global__ void k_scan3b(int* __restrict__ arr, const int* __restrict__ blocksum, int L) {
    int i = blockIdx.x * 256 + threadIdx.x;
    if (i < L) arr[i] += blocksum[blockIdx.x];
}

// Pass C: partition edges into bucket regions; per-chunk LDS cursors -> dense writes
__global__ void k_part(const int* __restrict__ src, const int* __restrict__ dst,
                       const float* __restrict__ ea, const int* __restrict__ gofs,
                       int2* __restrict__ tmp, int E, int CE, int NBK) {
    __shared__ int cur[256];
    int t = threadIdx.x;
    int c = blockIdx.x;
    if (t < NBK) cur[t] = gofs[t * 256 + c];
    __syncthreads();
    int lo = c * CE, hi = min(E, lo + CE);
    for (int e = lo + t; e < hi; e += 256) {
        int d = dst[e];
        int pos = atomicAdd(&cur[d >> 8], 1);
        tmp[pos] = make_int2(((d & 255) << 24) | (src[e] << 4), __float_as_int(ea[e]));
    }
}

// Pass D: fine sort within bucket via LDS histogram+scan; also emits row_ptr.
__global__ void k_fsort(const int2* __restrict__ tmp, const int* __restrict__ gofs,
                        int2* __restrict__ csr, int* __restrict__ row_ptr,
                        int N, int E, int NBK) {
    __shared__ int lcnt[256], lofs[256], lcur[256];
    int bkt = blockIdx.x;
    int t = threadIdx.x;
    int base = gofs[bkt * 256];
    int endv = (bkt == NBK - 1) ? E : gofs[(bkt + 1) * 256];
    int cnt = endv - base;
    lcnt[t] = 0;
    __syncthreads();
    for (int i = t; i < cnt; i += 256)
        atomicAdd(&lcnt[(unsigned)tmp[base + i].x >> 24], 1);
    __syncthreads();
    int v = lcnt[t];
    lofs[t] = v;
    __syncthreads();
    #pragma unroll
    for (int off = 1; off < 256; off <<= 1) {
        int add = (t >= off) ? lofs[t - off] : 0;
        __syncthreads();
        lofs[t] += add;
        __syncthreads();
    }
    int excl = lofs[t] - v;          // exclusive within bucket
    int nlo = bkt << 8;
    if (nlo + t < N) row_ptr[nlo + t] = base + excl;
    lcur[t] = base + excl;
    __syncthreads();
    for (int i = t; i < cnt; i += 256) {
        int2 e2 = tmp[base + i];
        int dl = (unsigned)e2.x >> 24;
        int pos = atomicAdd(&lcur[dl], 1);
        csr[pos] = make_int2(e2.x & 0x00FFFFFF, e2.y);
    }
    if (bkt == 0 && t == 0) row_ptr[N] = E;
}

// loop_ea[i] = (sum of incoming ea) / max(deg,1)
__global__ void k_loopea(const int* __restrict__ row_ptr, const int2* __restrict__ csr,
                         float* __restrict__ loop_ea, int N) {
    int i = blockIdx.x * blockDim.x + threadIdx.x;
    if (i >= N) return;
    int start = row_ptr[i], end = row_ptr[i + 1];
    float s = 0.0f;
    for (int k = start; k < end; ++k) s += __int_as_float(csr[k].y);
    loop_ea[i] = s / fmaxf((float)(end - start), 1.0f);
}

// ---------------- layer 1 ----------------

// One wave per dst node, lane = 2 channels. node forced wave-uniform via
// readfirstlane -> inner-loop loads become scalar s_loads. DPP head-reduce.
__global__ void k_l1_node(const int2* __restrict__ csr, const int* __restrict__ row_ptr,
                          const float* __restrict__ x, const float* __restrict__ loop_ea,
                          const float* __restrict__ Wl1, const float* __restrict__ bl1,
                          const float* __restrict__ Wr1, const float* __restrict__ br1,
                          const float* __restrict__ We1, const float* __restrict__ att1,
                          const float* __restrict__ bias1, float* __restrict__ h1, int N) {
    int node = blockIdx.x * (blockDim.x >> 6) + (threadIdx.x >> 6);
    if (node >= N) return;
    node = __builtin_amdgcn_readfirstlane(node);
    int lane = threadIdx.x & 63;
    int c = lane * 2;
    float wl00 = Wl1[c],       wl01 = Wl1[c + 1];
    float wl10 = Wl1[128 + c], wl11 = Wl1[128 + c + 1];
    float wl20 = Wl1[256 + c], wl21 = Wl1[256 + c + 1];
    float wl30 = Wl1[384 + c], wl31 = Wl1[384 + c + 1];
    float b0 = bl1[c], b1 = bl1[c + 1];
    float4 xv = *(const float4*)(x + (size_t)node * 4);
    float r0 = br1[c], r1 = br1[c + 1];
    r0 = fmaf(xv.x, Wr1[c],       r0); r1 = fmaf(xv.x, Wr1[c + 1],       r1);
    r0 = fmaf(xv.y, Wr1[128 + c], r0); r1 = fmaf(xv.y, Wr1[128 + c + 1], r1);
    r0 = fmaf(xv.z, Wr1[256 + c], r0); r1 = fmaf(xv.z, Wr1[256 + c + 1], r1);
    r0 = fmaf(xv.w, Wr1[384 + c], r0); r1 = fmaf(xv.w, Wr1[384 + c + 1], r1);
    float2 we = *(const float2*)(We1 + c);
    float2 at = *(const float2*)(att1 + c);
    at.x *= LOG2E; at.y *= LOG2E;   // fold exp -> exp2
    const char* xb = (const char*)x;

    #define VL0(xs) fmaf((xs).w, wl30, fmaf((xs).z, wl20, fmaf((xs).y, wl10, fmaf((xs).x, wl00, b0))))
    #define VL1(xs) fmaf((xs).w, wl31, fmaf((xs).z, wl21, fmaf((xs).y, wl11, fmaf((xs).x, wl01, b1))))

    int start = row_ptr[node];
    int deg   = row_ptr[node + 1] - start;
    const int2* crow = csr + start;

    // self-loop
    float vx = VL0(xv), vy = VL1(xv);
    float eav = loop_ea[node];
    float p = LRELU(vx + r0 + eav * we.x) * at.x + LRELU(vy + r1 + eav * we.y) * at.y;
    RED8(p);
    float a = exp2f(p);
    float den = a, accx = a * vx, accy = a * vy;
    int k = 0;
    for (; k + 4 <= deg; k += 4) {
        int2 pr0 = crow[k],     pr1 = crow[k + 1];
        int2 pr2 = crow[k + 2], pr3 = crow[k + 3];
        float e0 = __int_as_float(pr0.y), e1 = __int_as_float(pr1.y);
        float e2 = __int_as_float(pr2.y), e3 = __int_as_float(pr3.y);
        float4 x0 = *(const float4*)(xb + (unsigned)pr0.x);
        float4 x1 = *(const float4*)(xb + (unsigned)pr1.x);
        float4 x2 = *(const float4*)(xb + (unsigned)pr2.x);
        float4 x3 = *(const float4*)(xb + (unsigned)pr3.x);
        float v0x = VL0(x0), v0y = VL1(x0);
        float v1x = VL0(x1), v1y = VL1(x1);
        float v2x = VL0(x2), v2y = VL1(x2);
        float v3x = VL0(x3), v3y = VL1(x3);
        float p0 = LRELU(v0x + r0 + e0 * we.x) * at.x + LRELU(v0y + r1 + e0 * we.y) * at.y;
        float p1 = LRELU(v1x + r0 + e1 * we.x) * at.x + LRELU(v1y + r1 + e1 * we.y) * at.y;
        float p2 = LRELU(v2x + r0 + e2 * we.x) * at.x + LRELU(v2y + r1 + e2 * we.y) * at.y;
        float p3 = LRELU(v3x + r0 + e3 * we.x) * at.x + LRELU(v3y + r1 + e3 * we.y) * at.y;
        RED8(p0); RED8(p1); RED8(p2); RED8(p3);
        float a0 = exp2f(p0), a1 = exp2f(p1), a2 = exp2f(p2), a3 = exp2f(p3);
        den += (a0 + a1) + (a2 + a3);
        accx = fmaf(a0, v0x, accx); accy = fmaf(a0, v0y, accy);
        accx = fmaf(a1, v1x, accx); accy = fmaf(a1, v1y, accy);
        accx = fmaf(a2, v2x, accx); accy = fmaf(a2, v2y, accy);
        accx = fmaf(a3, v3x, accx); accy = fmaf(a3, v3y, accy);
    }
    for (; k < deg; ++k) {
        int2 pr = crow[k];
        float ee = __int_as_float(pr.y);
        float4 xs = *(const float4*)(xb + (unsigned)pr.x);
        float vsx = VL0(xs), vsy = VL1(xs);
        float pp = LRELU(vsx + r0 + ee * we.x) * at.x + LRELU(vsy + r1 + ee * we.y) * at.y;
        RED8(pp);
        float aa = exp2f(pp);
        den += aa;
        accx = fmaf(aa, vsx, accx);
        accy = fmaf(aa, vsy, accy);
    }
    #undef VL0
    #undef VL1
    float inv = 1.0f / den;
    float o0 = fmaf(accx, inv, bias1[c]);
    float o1 = fmaf(accy, inv, bias1[c + 1]);
    o0 = o0 > 0.0f ? o0 : expm1f(o0);
    o1 = o1 > 0.0f ? o1 : expm1f(o1);
    *(float2*)(h1 + (size_t)node * 128 + c) = make_float2(o0, o1);
}

// ---------------- layer 2 ----------------

__global__ void k_l2_lin(const float* __restrict__ h1, const float* __restrict__ Wl2,
                         const float* __restrict__ bl2, const float* __restrict__ Wr2,
                         const float* __restrict__ br2, float* __restrict__ xl2,
                         float* __restrict__ xr2, int N) {
    int t = blockIdx.x * blockDim.x + threadIdx.x;
    if (t >= N * 8) return;
    int i = t >> 3, j = t & 7;
    float accl = bl2[j], accr = br2[j];
    const float* row = h1 + (size_t)i * 128;
    #pragma unroll 4
    for (int k = 0; k < 128; k += 4) {
        float4 hv = *(const float4*)(row + k);
        accl = fmaf(hv.x, Wl2[k * 8 + j], accl);       accr = fmaf(hv.x, Wr2[k * 8 + j], accr);
        accl = fmaf(hv.y, Wl2[(k + 1) * 8 + j], accl); accr = fmaf(hv.y, Wr2[(k + 1) * 8 + j], accr);
        accl = fmaf(hv.z, Wl2[(k + 2) * 8 + j], accl); accr = fmaf(hv.z, Wr2[(k + 2) * 8 + j], accr);
        accl = fmaf(hv.w, Wl2[(k + 3) * 8 + j], accl); accr = fmaf(hv.w, Wr2[(k + 3) * 8 + j], accr);
    }
    xl2[t] = accl;
    xr2[t] = accr;
}

// 8 lanes per dst node (8 nodes per wave), lane = edge within group.
__global__ void k_l2_node(const int2* __restrict__ csr, const int* __restrict__ row_ptr,
                          const float* __restrict__ xl2, const float* __restrict__ xr2,
                          const float* __restrict__ loop_ea,
                          const float* __restrict__ We2, const float* __restrict__ att2,
                          const float* __restrict__ bias2, float* __restrict__ h2, int N) {
    int t = blockIdx.x * blockDim.x + threadIdx.x;
    int node = t >> 3;
    int lane = t & 7;
    if (node >= N) return;
    float4 ra = *(const float4*)(xr2 + (size_t)node * 8);
    float4 rb = *(const float4*)(xr2 + (size_t)node * 8 + 4);
    float r[8] = {ra.x, ra.y, ra.z, ra.w, rb.x, rb.y, rb.z, rb.w};
    float we[8], at[8];
    #pragma unroll
    for (int cc = 0; cc < 8; ++cc) { we[cc] = We2[cc]; at[cc] = att2[cc] * LOG2E; }
    const char* xlb = (const char*)xl2;
    int start = row_ptr[node], deg = row_ptr[node + 1] - start;
    int total = deg + 1;          // + self loop
    float den = 0.0f;
    float acc[8];
    #pragma unroll
    for (int cc = 0; cc < 8; ++cc) acc[cc] = 0.0f;
    for (int base = 0; base < total; base += 8) {
        int e = base + lane;
        float a = 0.0f;
        float l[8];
        #pragma unroll
        for (int cc = 0; cc < 8; ++cc) l[cc] = 0.0f;
        if (e < total) {
            const float* lp;
            float eav;
            if (e < deg) {
                int2 pr = csr[start + e];
                lp = (const float*)(xlb + 2u * (unsigned)pr.x);   // src*32 bytes
                eav = __int_as_float(pr.y);
            } else {
                lp = xl2 + (size_t)node * 8;
                eav = loop_ea[node];
            }
            float4 la = *(const float4*)lp;
            float4 lb = *(const float4*)(lp + 4);
            l[0] = la.x; l[1] = la.y; l[2] = la.z; l[3] = la.w;
            l[4] = lb.x; l[5] = lb.y; l[6] = lb.z; l[7] = lb.w;
            float p = 0.0f;
            #pragma unroll
            for (int cc = 0; cc < 8; ++cc) {
                float m = l[cc] + r[cc] + eav * we[cc];
                p = fmaf(LRELU(m), at[cc], p);
            }
            a = exp2f(p);
        }
        float w0 = a;
        float w1 = a * l[0], w2 = a * l[1], w3 = a * l[2], w4 = a * l[3];
        float w5 = a * l[4], w6 = a * l[5], w7 = a * l[6], w8 = a * l[7];
        RED8(w0);
        RED8(w1); RED8(w2); RED8(w3); RED8(w4);
        RED8(w5); RED8(w6); RED8(w7); RED8(w8);
        den += w0;
        acc[0] += w1; acc[1] += w2; acc[2] += w3; acc[3] += w4;
        acc[4] += w5; acc[5] += w6; acc[6] += w7; acc[7] += w8;
    }
    if (lane == 0) {
        float inv = 1.0f / den;
        float o[8];
        #pragma unroll
        for (int cc = 0; cc < 8; ++cc) {
            float v = fmaf(acc[cc], inv, bias2[cc]);
            o[cc] = v > 0.0f ? v : expm1f(v);
        }
        *(float4*)(h2 + (size_t)node * 8)     = make_float4(o[0], o[1], o[2], o[3]);
        *(float4*)(h2 + (size_t)node * 8 + 4) = make_float4(o[4], o[5], o[6], o[7]);
    }
}

// One block per graph; batch is sorted -> binary-search the segment.
__global__ void k_pool(const float* __restrict__ h2, const int* __restrict__ batch,
                       const float* __restrict__ W3, const float* __restrict__ b3,
                       float* __restrict__ out, int N) {
    int g = blockIdx.x;
    int lo = 0, hi = N;
    while (lo < hi) { int mid = (lo + hi) >> 1; if (batch[mid] < g) lo = mid + 1; else hi = mid; }
    int start = lo;
    int lo2 = start, hi2 = N;
    while (lo2 < hi2) { int mid = (lo2 + hi2) >> 1; if (batch[mid] < g + 1) lo2 = mid + 1; else hi2 = mid; }
    int end = lo2;
    int cnt = end - start;
    int t = threadIdx.x;
    int c = t & 7, rg = t >> 3;
    float s = 0.0f;
    for (int i = start + rg; i < end; i += 32) s += h2[(size_t)i * 8 + c];
    __shared__ float sm[256];
    sm[t] = s;
    __syncthreads();
    #pragma unroll
    for (int off = 16; off >= 1; off >>= 1) {
        if (rg < off) sm[t] += sm[t + off * 8];
        __syncthreads();
    }
    if (t == 0) {
        float inv = 1.0f / fmaxf((float)cnt, 1.0f);
        float acc = b3[0];
        #pragma unroll
        for (int cc = 0; cc < 8; ++cc) acc = fmaf(sm[cc] * inv, W3[cc], acc);
        out[g] = acc;
    }
}

extern "C" void kernel_launch(void* const* d_in, const int* in_sizes, int n_in,
                              void* d_out, int out_size, void* d_ws, size_t ws_size,
                              hipStream_t stream) {
    const float* x     = (const float*)d_in[0];
    const int*   ei    = (const int*)d_in[1];
    const float* ea    = (const float*)d_in[2];
    const int*   batch = (const int*)d_in[3];
    const float* Wl1 = (const float*)d_in[4];
    const float* bl1 = (const float*)d_in[5];
    const float* Wr1 = (const float*)d_in[6];
    const float* br1 = (const float*)d_in[7];
    const float* We1 = (const float*)d_in[8];
    const float* att1 = (const float*)d_in[9];
    const float* bias1 = (const float*)d_in[10];
    const float* Wl2 = (const float*)d_in[11];
    const float* bl2 = (const float*)d_in[12];
    const float* Wr2 = (const float*)d_in[13];
    const float* br2 = (const float*)d_in[14];
    const float* We2 = (const float*)d_in[15];
    const float* att2 = (const float*)d_in[16];
    const float* bias2 = (const float*)d_in[17];
    const float* W3 = (const float*)d_in[18];
    const float* b3 = (const float*)d_in[19];

    const int N  = in_sizes[0] / 4;
    const int E  = in_sizes[1] / 2;
    const int G  = out_size;
    const int* src = ei;
    const int* dst = ei + E;

    const int NBK = (N + 255) >> 8;          // buckets of 256 nodes, <= 256
    const int NCH = 256;                     // edge chunks
    const int CE  = (E + NCH - 1) / NCH;     // edges per chunk
    const int L   = NBK * 256;               // count-matrix length
    const int nbN = (N + 255) / 256;

    int* w = (int*)d_ws;
    int* gofs     = w; w += L + 1;           // counts -> offsets (in-place scan)
    int* blocksum = w; w += 256;
    int* row_ptr  = w; w += N + 1;
    float* loop_ea = (float*)w; w += N;
    float* h1  = (float*)w; w += (size_t)N * 128;
    float* xl2 = (float*)w; w += (size_t)N * 8;
    float* xr2 = (float*)w; w += (size_t)N * 8;
    int2* tmp = (int2*)w; w += (size_t)E * 2;
    int2* csr = (int2*)w; w += (size_t)E * 2;
    float* h2 = h1;                          // h1 dead after k_l2_lin

    // CSR build: two-level counting sort
    k_bcnt<<<NCH, 256, 0, stream>>>(dst, gofs, E, CE, NBK);
    k_scan1<<<NBK, 256, 0, stream>>>(gofs, gofs, blocksum, L);
    k_scan2<<<1, 256, 0, stream>>>(blocksum, NBK);
    k_scan3b<<<NBK, 256, 0, stream>>>(gofs, blocksum, L);
    k_part<<<NCH, 256, 0, stream>>>(src, dst, ea, gofs, tmp, E, CE, NBK);
    k_fsort<<<NBK, 256, 0, stream>>>(tmp, gofs, csr, row_ptr, N, E, NBK);
    k_loopea<<<nbN, 256, 0, stream>>>(row_ptr, csr, loop_ea, N);

    // layer 1
    k_l1_node<<<(N + 3) / 4, 256, 0, stream>>>(csr, row_ptr, x, loop_ea,
                                               Wl1, bl1, Wr1, br1, We1, att1, bias1, h1, N);
    // layer 2
    k_l2_lin<<<((size_t)N * 8 + 255) / 256, 256, 0, stream>>>(h1, Wl2, bl2, Wr2, br2,
                                                              xl2, xr2, N);
    k_l2_node<<<((size_t)N * 8 + 255) / 256, 256, 0, stream>>>(csr, row_ptr, xl2, xr2,
                                                               loop_ea, We2, att2, bias2, h2, N);
    // pool + final linear
    k_pool<<<G, 256, 0, stream>>>(h2, batch, W3, b3, (float*)d_out, N);
}